// Round 7
// baseline (1012.945 us; speedup 1.0000x reference)
//
#include <hip/hip_runtime.h>
#include <math.h>

#define N_NODES 100000
#define N_EDGES 1600000
#define NF 64
#define ORDER 8
#define NBLK 391          // ceil(N_NODES/256)

// ---------------- CSR build (once per launch) ----------------

__global__ __launch_bounds__(256) void zero_ints(int* __restrict__ c, int n) {
  int i = blockIdx.x * 256 + threadIdx.x;
  if (i < n) c[i] = 0;
}

__global__ __launch_bounds__(256) void hist_kernel(const int* __restrict__ dst,
                                                   int* __restrict__ counts) {
  int e = blockIdx.x * 256 + threadIdx.x;
  if (e < N_EDGES) atomicAdd(&counts[dst[e]], 1);
}

__global__ __launch_bounds__(256) void reduce_counts(const int* __restrict__ counts,
                                                     int* __restrict__ blockSums) {
  int i = blockIdx.x * 256 + threadIdx.x;
  int v = (i < N_NODES) ? counts[i] : 0;
  #pragma unroll
  for (int m = 1; m < 64; m <<= 1) v += __shfl_xor(v, m, 64);
  __shared__ int s[4];
  if ((threadIdx.x & 63) == 0) s[threadIdx.x >> 6] = v;
  __syncthreads();
  if (threadIdx.x == 0) blockSums[blockIdx.x] = s[0] + s[1] + s[2] + s[3];
}

__global__ __launch_bounds__(512) void scan_partials(const int* __restrict__ blockSums,
                                                     int* __restrict__ blockOffs) {
  __shared__ int s[512];
  int t = threadIdx.x;
  int v = (t < NBLK) ? blockSums[t] : 0;
  s[t] = v;
  __syncthreads();
  for (int off = 1; off < 512; off <<= 1) {
    int u = (t >= off) ? s[t - off] : 0;
    __syncthreads();
    s[t] += u;
    __syncthreads();
  }
  if (t < NBLK) blockOffs[t] = s[t] - v;   // exclusive
}

__global__ __launch_bounds__(256) void scan_blocks(const int* __restrict__ counts,
    const int* __restrict__ blockOffs, int* __restrict__ row_start,
    int* __restrict__ cursor) {
  __shared__ int s[256];
  int t = threadIdx.x;
  int i = blockIdx.x * 256 + t;
  int v = (i < N_NODES) ? counts[i] : 0;
  s[t] = v;
  __syncthreads();
  for (int off = 1; off < 256; off <<= 1) {
    int u = (t >= off) ? s[t - off] : 0;
    __syncthreads();
    s[t] += u;
    __syncthreads();
  }
  int excl = s[t] - v + blockOffs[blockIdx.x];
  if (i < N_NODES) { row_start[i] = excl; cursor[i] = excl; }
  if (i == N_NODES - 1) row_start[N_NODES] = excl + v;
}

__global__ __launch_bounds__(256) void fill_kernel(const int* __restrict__ src,
    const int* __restrict__ dst, const float* __restrict__ ew,
    int* __restrict__ cursor, int2* __restrict__ adj) {
  int e = blockIdx.x * 256 + threadIdx.x;
  if (e >= N_EDGES) return;
  int d = dst[e];
  int pos = atomicAdd(&cursor[d], 1);
  adj[pos] = make_int2(src[e], __float_as_int(ew[e]));
}

// sort each row's edges ascending by src -> concurrent gathers cluster in a
// narrow src band (XCD-L2 locality across all 8 spmm rounds).
__global__ __launch_bounds__(256) void sort_rows(const int* __restrict__ row_start,
                                                 int2* __restrict__ adj) {
  int n = blockIdx.x * 256 + threadIdx.x;
  if (n >= N_NODES) return;
  const int beg = row_start[n];
  const int end = row_start[n + 1];
  for (int i = beg + 1; i < end; ++i) {
    int2 key = adj[i];
    int j = i - 1;
    while (j >= beg && adj[j].x > key.x) { adj[j + 1] = adj[j]; --j; }
    adj[j + 1] = key;
  }
}

// W1 [256][47] -> W1T [47][256]
__global__ __launch_bounds__(256) void transpose_w1(const float* __restrict__ W1,
                                                    float* __restrict__ W1T) {
  int k = threadIdx.x;
  for (int c = 0; c < 47; ++c) W1T[c * 256 + k] = W1[k * 47 + c];
}

// ---------------- propagation ----------------

__global__ __launch_bounds__(256) void init_kernel(const float4* __restrict__ X,
    float4* __restrict__ xc, float4* __restrict__ prop, int n4) {
  int i = blockIdx.x * 256 + threadIdx.x;
  if (i >= n4) return;
  float4 v = X[i];
  v.x *= 0.5f; v.y *= 0.5f; v.z *= 0.5f; v.w *= 0.5f;
  xc[i] = v;
  prop[i] = v;
}

// gather-sum per dst node: 32 lanes/node, float2/lane, software-pipelined
// batch-of-4 edge prefetch. Rows are src-sorted for cache locality.
__global__ __launch_bounds__(256) void spmm_csr(const float2* __restrict__ x,
    const int* __restrict__ row_start, const int2* __restrict__ adj,
    float2* __restrict__ xn, float2* __restrict__ prop) {
  const int node = blockIdx.x * 8 + (threadIdx.x >> 5);   // 100000 % 8 == 0
  const int f2 = threadIdx.x & 31;
  const int beg = row_start[node];
  const int end = row_start[node + 1];
  const int nfull = (end - beg) >> 2;
  float2 a0 = make_float2(0.f, 0.f), a1 = a0;

  int2 e0, e1, e2, e3;
  float2 v0, v1, v2, v3;
  if (nfull > 0) {
    e0 = adj[beg];     e1 = adj[beg + 1]; e2 = adj[beg + 2]; e3 = adj[beg + 3];
    v0 = x[(size_t)e0.x * 32 + f2];
    v1 = x[(size_t)e1.x * 32 + f2];
    v2 = x[(size_t)e2.x * 32 + f2];
    v3 = x[(size_t)e3.x * 32 + f2];
  }
  for (int b = 1; b < nfull; ++b) {
    const int q = beg + 4 * b;
    int2 g0 = adj[q], g1 = adj[q + 1], g2 = adj[q + 2], g3 = adj[q + 3];
    float2 u0 = x[(size_t)g0.x * 32 + f2];
    float2 u1 = x[(size_t)g1.x * 32 + f2];
    float2 u2 = x[(size_t)g2.x * 32 + f2];
    float2 u3 = x[(size_t)g3.x * 32 + f2];
    float w0 = __int_as_float(e0.y), w1 = __int_as_float(e1.y);
    float w2 = __int_as_float(e2.y), w3 = __int_as_float(e3.y);
    a0.x = fmaf(v0.x, w0, a0.x); a0.y = fmaf(v0.y, w0, a0.y);
    a1.x = fmaf(v1.x, w1, a1.x); a1.y = fmaf(v1.y, w1, a1.y);
    a0.x = fmaf(v2.x, w2, a0.x); a0.y = fmaf(v2.y, w2, a0.y);
    a1.x = fmaf(v3.x, w3, a1.x); a1.y = fmaf(v3.y, w3, a1.y);
    e0 = g0; e1 = g1; e2 = g2; e3 = g3;
    v0 = u0; v1 = u1; v2 = u2; v3 = u3;
  }
  if (nfull > 0) {
    float w0 = __int_as_float(e0.y), w1 = __int_as_float(e1.y);
    float w2 = __int_as_float(e2.y), w3 = __int_as_float(e3.y);
    a0.x = fmaf(v0.x, w0, a0.x); a0.y = fmaf(v0.y, w0, a0.y);
    a1.x = fmaf(v1.x, w1, a1.x); a1.y = fmaf(v1.y, w1, a1.y);
    a0.x = fmaf(v2.x, w2, a0.x); a0.y = fmaf(v2.y, w2, a0.y);
    a1.x = fmaf(v3.x, w3, a1.x); a1.y = fmaf(v3.y, w3, a1.y);
  }
  for (int p = beg + 4 * nfull; p < end; ++p) {
    int2 e = adj[p];
    float2 v = x[(size_t)e.x * 32 + f2];
    float w = __int_as_float(e.y);
    a0.x = fmaf(v.x, w, a0.x); a0.y = fmaf(v.y, w, a0.y);
  }
  a0.x += a1.x; a0.y += a1.y;
  const size_t o = (size_t)node * 32 + f2;
  xn[o] = a0;
  float2 pr = prop[o];
  pr.x += a0.x; pr.y += a0.y;
  prop[o] = pr;
}

// ---------------- fused tail, register-blocked, LDS-aliased ----------------
// 32 nodes/block. Xp = normalize(prop/9); h = normalize(relu(Xp@W0+b0)); out = h@W1+b1.
// sXTn aliases the head of sHn (dead after GEMM1's barrier) -> 38.7 KB LDS, 4 blocks/CU.
__global__ __launch_bounds__(256) void tail_kernel(
    const float* __restrict__ prop, const float* __restrict__ W0,
    const float* __restrict__ b0, const float* __restrict__ W1T,
    const float* __restrict__ b1, float* __restrict__ out) {
  __shared__ __align__(16) float sHn[32][268];    // 34304 B; head doubles as sXTn[32][68]
  __shared__ float sPart[32][33];
  __shared__ float sHinv[32];
  float (*sXTn)[68] = reinterpret_cast<float (*)[68]>(&sHn[0][0]);

  const int t = threadIdx.x;
  const int lane = t & 63;
  const int w = t >> 6;
  const int base = blockIdx.x * 32;   // 3125 * 32 == 100000 exactly

  // ---- load + Xp-normalize: wave handles one node per iter, store node-major ----
  #pragma unroll
  for (int it = 0; it < 8; ++it) {
    const int nb = it * 4 + w;
    float v = prop[(size_t)(base + nb) * NF + lane];
    float ss = v * v;
    #pragma unroll
    for (int m = 1; m < 64; m <<= 1) ss += __shfl_xor(ss, m, 64);
    float nrm = sqrtf(ss) * (1.0f / 9.0f);
    float scale = (1.0f / 9.0f) / (1e-12f + nrm);
    sXTn[nb][lane] = v * scale;
  }
  __syncthreads();

  // ---- GEMM1: thread = 8 cols (8*tc..) x 4 nodes (tn, tn+8, tn+16, tn+24) ----
  const int tc = t >> 3;   // 0..31
  const int tn = t & 7;    // 0..7
  const float4* W0v = (const float4*)W0;
  float4 b0a = ((const float4*)b0)[2 * tc];
  float4 b0b = ((const float4*)b0)[2 * tc + 1];
  float acc[4][8];
  #pragma unroll
  for (int j = 0; j < 4; ++j) {
    acc[j][0] = b0a.x; acc[j][1] = b0a.y; acc[j][2] = b0a.z; acc[j][3] = b0a.w;
    acc[j][4] = b0b.x; acc[j][5] = b0b.y; acc[j][6] = b0b.z; acc[j][7] = b0b.w;
  }
  for (int k = 0; k < NF; k += 4) {
    float xsA[4], xsB[4], xsC[4], xsD[4];
    *(float4*)xsA = *(const float4*)&sXTn[tn][k];
    *(float4*)xsB = *(const float4*)&sXTn[tn + 8][k];
    *(float4*)xsC = *(const float4*)&sXTn[tn + 16][k];
    *(float4*)xsD = *(const float4*)&sXTn[tn + 24][k];
    #pragma unroll
    for (int kk = 0; kk < 4; ++kk) {
      float4 wa = W0v[(k + kk) * 64 + 2 * tc];
      float4 wb = W0v[(k + kk) * 64 + 2 * tc + 1];
      acc[0][0] = fmaf(xsA[kk], wa.x, acc[0][0]);
      acc[0][1] = fmaf(xsA[kk], wa.y, acc[0][1]);
      acc[0][2] = fmaf(xsA[kk], wa.z, acc[0][2]);
      acc[0][3] = fmaf(xsA[kk], wa.w, acc[0][3]);
      acc[0][4] = fmaf(xsA[kk], wb.x, acc[0][4]);
      acc[0][5] = fmaf(xsA[kk], wb.y, acc[0][5]);
      acc[0][6] = fmaf(xsA[kk], wb.z, acc[0][6]);
      acc[0][7] = fmaf(xsA[kk], wb.w, acc[0][7]);
      acc[1][0] = fmaf(xsB[kk], wa.x, acc[1][0]);
      acc[1][1] = fmaf(xsB[kk], wa.y, acc[1][1]);
      acc[1][2] = fmaf(xsB[kk], wa.z, acc[1][2]);
      acc[1][3] = fmaf(xsB[kk], wa.w, acc[1][3]);
      acc[1][4] = fmaf(xsB[kk], wb.x, acc[1][4]);
      acc[1][5] = fmaf(xsB[kk], wb.y, acc[1][5]);
      acc[1][6] = fmaf(xsB[kk], wb.z, acc[1][6]);
      acc[1][7] = fmaf(xsB[kk], wb.w, acc[1][7]);
      acc[2][0] = fmaf(xsC[kk], wa.x, acc[2][0]);
      acc[2][1] = fmaf(xsC[kk], wa.y, acc[2][1]);
      acc[2][2] = fmaf(xsC[kk], wa.z, acc[2][2]);
      acc[2][3] = fmaf(xsC[kk], wa.w, acc[2][3]);
      acc[2][4] = fmaf(xsC[kk], wb.x, acc[2][4]);
      acc[2][5] = fmaf(xsC[kk], wb.y, acc[2][5]);
      acc[2][6] = fmaf(xsC[kk], wb.z, acc[2][6]);
      acc[2][7] = fmaf(xsC[kk], wb.w, acc[2][7]);
      acc[3][0] = fmaf(xsD[kk], wa.x, acc[3][0]);
      acc[3][1] = fmaf(xsD[kk], wa.y, acc[3][1]);
      acc[3][2] = fmaf(xsD[kk], wa.z, acc[3][2]);
      acc[3][3] = fmaf(xsD[kk], wa.w, acc[3][3]);
      acc[3][4] = fmaf(xsD[kk], wb.x, acc[3][4]);
      acc[3][5] = fmaf(xsD[kk], wb.y, acc[3][5]);
      acc[3][6] = fmaf(xsD[kk], wb.z, acc[3][6]);
      acc[3][7] = fmaf(xsD[kk], wb.w, acc[3][7]);
    }
  }

  // relu + per-node partial sumsq
  #pragma unroll
  for (int j = 0; j < 4; ++j) {
    float part = 0.0f;
    #pragma unroll
    for (int i = 0; i < 8; ++i) {
      float a = fmaxf(acc[j][i], 0.0f);
      acc[j][i] = a;
      part = fmaf(a, a, part);
    }
    sPart[tn + 8 * j][tc] = part;
  }
  __syncthreads();

  if (t < 32) {
    float s = 0.0f;
    #pragma unroll
    for (int i = 0; i < 32; ++i) s += sPart[t][i];
    sHinv[t] = 1.0f / (1e-12f + sqrtf(s));
  }
  __syncthreads();

  // scale + store h node-major (clobbers the dead sXTn alias region)
  #pragma unroll
  for (int j = 0; j < 4; ++j) {
    float sc = sHinv[tn + 8 * j];
    float4 ha, hb;
    ha.x = acc[j][0] * sc; ha.y = acc[j][1] * sc;
    ha.z = acc[j][2] * sc; ha.w = acc[j][3] * sc;
    hb.x = acc[j][4] * sc; hb.y = acc[j][5] * sc;
    hb.z = acc[j][6] * sc; hb.w = acc[j][7] * sc;
    *(float4*)&sHn[tn + 8 * j][8 * tc] = ha;
    *(float4*)&sHn[tn + 8 * j][8 * tc + 4] = hb;
  }
  __syncthreads();

  // ---- GEMM2: thread = 3 cols {tc2, tc2+16, tc2+32} x 2 nodes {tn2, tn2+16} ----
  const int tn2 = t & 15;
  const int tc2 = t >> 4;   // 0..15
  const bool c3 = (tc2 < 15);
  const float4* w1a = (const float4*)&W1T[tc2 * 256];
  const float4* w1b = (const float4*)&W1T[(tc2 + 16) * 256];
  const float4* w1c = (const float4*)&W1T[(c3 ? tc2 + 32 : tc2) * 256];
  float a00 = b1[tc2], a01 = b1[tc2 + 16], a02 = c3 ? b1[tc2 + 32] : 0.0f;
  float a10 = a00,     a11 = a01,          a12 = a02;
  for (int k4 = 0; k4 < 64; ++k4) {
    float4 h0 = *(const float4*)&sHn[tn2][4 * k4];
    float4 h1 = *(const float4*)&sHn[tn2 + 16][4 * k4];
    float4 wa = w1a[k4];
    float4 wb = w1b[k4];
    float4 wc = w1c[k4];
    a00 = fmaf(h0.x, wa.x, a00); a00 = fmaf(h0.y, wa.y, a00);
    a00 = fmaf(h0.z, wa.z, a00); a00 = fmaf(h0.w, wa.w, a00);
    a01 = fmaf(h0.x, wb.x, a01); a01 = fmaf(h0.y, wb.y, a01);
    a01 = fmaf(h0.z, wb.z, a01); a01 = fmaf(h0.w, wb.w, a01);
    a02 = fmaf(h0.x, wc.x, a02); a02 = fmaf(h0.y, wc.y, a02);
    a02 = fmaf(h0.z, wc.z, a02); a02 = fmaf(h0.w, wc.w, a02);
    a10 = fmaf(h1.x, wa.x, a10); a10 = fmaf(h1.y, wa.y, a10);
    a10 = fmaf(h1.z, wa.z, a10); a10 = fmaf(h1.w, wa.w, a10);
    a11 = fmaf(h1.x, wb.x, a11); a11 = fmaf(h1.y, wb.y, a11);
    a11 = fmaf(h1.z, wb.z, a11); a11 = fmaf(h1.w, wb.w, a11);
    a12 = fmaf(h1.x, wc.x, a12); a12 = fmaf(h1.y, wc.y, a12);
    a12 = fmaf(h1.z, wc.z, a12); a12 = fmaf(h1.w, wc.w, a12);
  }
  {
    const size_t n0 = (size_t)(base + tn2) * 47;
    const size_t n1 = (size_t)(base + tn2 + 16) * 47;
    out[n0 + tc2] = a00;
    out[n0 + tc2 + 16] = a01;
    if (c3) out[n0 + tc2 + 32] = a02;
    out[n1 + tc2] = a10;
    out[n1 + tc2 + 16] = a11;
    if (c3) out[n1 + tc2 + 32] = a12;
  }
}

extern "C" void kernel_launch(void* const* d_in, const int* in_sizes, int n_in,
                              void* d_out, int out_size, void* d_ws, size_t ws_size,
                              hipStream_t stream) {
  (void)in_sizes; (void)n_in; (void)out_size; (void)ws_size;
  const float* X   = (const float*)d_in[0];
  const int*   src = (const int*)d_in[1];
  const int*   dst = (const int*)d_in[2];
  const float* ew  = (const float*)d_in[3];
  const float* W0  = (const float*)d_in[4];
  const float* b0  = (const float*)d_in[5];
  const float* W1  = (const float*)d_in[6];
  const float* b1  = (const float*)d_in[7];
  float* out = (float*)d_out;

  const size_t nf = (size_t)N_NODES * NF;
  float* bufA = (float*)d_ws;
  float* bufB = bufA + nf;
  float* prop = bufB + nf;
  int* counts     = (int*)(prop + nf);
  int* row_start  = counts + N_NODES;            // N_NODES+1
  int* cursor     = row_start + (N_NODES + 1);
  int* blockSums  = cursor + N_NODES;
  int* blockOffs  = blockSums + NBLK;
  float* W1T      = (float*)(((uintptr_t)(blockOffs + NBLK) + 15) & ~(uintptr_t)15);
  int2* adj       = (int2*)(((uintptr_t)(W1T + 47 * 256) + 15) & ~(uintptr_t)15);

  const int eblocks = (N_EDGES + 255) / 256;

  zero_ints<<<NBLK, 256, 0, stream>>>(counts, N_NODES);
  hist_kernel<<<eblocks, 256, 0, stream>>>(dst, counts);
  reduce_counts<<<NBLK, 256, 0, stream>>>(counts, blockSums);
  scan_partials<<<1, 512, 0, stream>>>(blockSums, blockOffs);
  scan_blocks<<<NBLK, 256, 0, stream>>>(counts, blockOffs, row_start, cursor);
  fill_kernel<<<eblocks, 256, 0, stream>>>(src, dst, ew, cursor, adj);
  sort_rows<<<NBLK, 256, 0, stream>>>(row_start, adj);
  transpose_w1<<<1, 256, 0, stream>>>(W1, W1T);

  const int n4 = (int)(nf / 4);
  init_kernel<<<(n4 + 255) / 256, 256, 0, stream>>>(
      (const float4*)X, (float4*)bufA, (float4*)prop, n4);

  float* xc = bufA;
  float* xn = bufB;
  for (int r = 0; r < ORDER; ++r) {
    spmm_csr<<<N_NODES / 8, 256, 0, stream>>>(
        (const float2*)xc, row_start, adj, (float2*)xn, (float2*)prop);
    float* tmp = xc; xc = xn; xn = tmp;
  }

  tail_kernel<<<N_NODES / 32, 256, 0, stream>>>(prop, W0, b0, W1T, b1, out);
}

// Round 8
// 843.206 us; speedup vs baseline: 1.2013x; 1.2013x over previous
//
#include <hip/hip_runtime.h>
#include <hip/hip_fp16.h>
#include <math.h>

#define N_NODES 100000
#define N_EDGES 1600000
#define NF 64
#define ORDER 8
#define NBLK 391          // ceil(N_NODES/256)

// ---------------- CSR build (once per launch) ----------------

__global__ __launch_bounds__(256) void zero_ints(int* __restrict__ c, int n) {
  int i = blockIdx.x * 256 + threadIdx.x;
  if (i < n) c[i] = 0;
}

__global__ __launch_bounds__(256) void hist_kernel(const int* __restrict__ dst,
                                                   int* __restrict__ counts) {
  int e = blockIdx.x * 256 + threadIdx.x;
  if (e < N_EDGES) atomicAdd(&counts[dst[e]], 1);
}

__global__ __launch_bounds__(256) void reduce_counts(const int* __restrict__ counts,
                                                     int* __restrict__ blockSums) {
  int i = blockIdx.x * 256 + threadIdx.x;
  int v = (i < N_NODES) ? counts[i] : 0;
  #pragma unroll
  for (int m = 1; m < 64; m <<= 1) v += __shfl_xor(v, m, 64);
  __shared__ int s[4];
  if ((threadIdx.x & 63) == 0) s[threadIdx.x >> 6] = v;
  __syncthreads();
  if (threadIdx.x == 0) blockSums[blockIdx.x] = s[0] + s[1] + s[2] + s[3];
}

__global__ __launch_bounds__(512) void scan_partials(const int* __restrict__ blockSums,
                                                     int* __restrict__ blockOffs) {
  __shared__ int s[512];
  int t = threadIdx.x;
  int v = (t < NBLK) ? blockSums[t] : 0;
  s[t] = v;
  __syncthreads();
  for (int off = 1; off < 512; off <<= 1) {
    int u = (t >= off) ? s[t - off] : 0;
    __syncthreads();
    s[t] += u;
    __syncthreads();
  }
  if (t < NBLK) blockOffs[t] = s[t] - v;   // exclusive
}

__global__ __launch_bounds__(256) void scan_blocks(const int* __restrict__ counts,
    const int* __restrict__ blockOffs, int* __restrict__ row_start,
    int* __restrict__ cursor) {
  __shared__ int s[256];
  int t = threadIdx.x;
  int i = blockIdx.x * 256 + t;
  int v = (i < N_NODES) ? counts[i] : 0;
  s[t] = v;
  __syncthreads();
  for (int off = 1; off < 256; off <<= 1) {
    int u = (t >= off) ? s[t - off] : 0;
    __syncthreads();
    s[t] += u;
    __syncthreads();
  }
  int excl = s[t] - v + blockOffs[blockIdx.x];
  if (i < N_NODES) { row_start[i] = excl; cursor[i] = excl; }
  if (i == N_NODES - 1) row_start[N_NODES] = excl + v;
}

__global__ __launch_bounds__(256) void fill_kernel(const int* __restrict__ src,
    const int* __restrict__ dst, const float* __restrict__ ew,
    int* __restrict__ cursor, int2* __restrict__ adj) {
  int e = blockIdx.x * 256 + threadIdx.x;
  if (e >= N_EDGES) return;
  int d = dst[e];
  int pos = atomicAdd(&cursor[d], 1);
  adj[pos] = make_int2(src[e], __float_as_int(ew[e]));
}

// W1 [256][47] -> W1T [47][256]
__global__ __launch_bounds__(256) void transpose_w1(const float* __restrict__ W1,
                                                    float* __restrict__ W1T) {
  int k = threadIdx.x;
  for (int c = 0; c < 47; ++c) W1T[c * 256 + k] = W1[k * 47 + c];
}

// ---------------- propagation ----------------

__global__ __launch_bounds__(256) void init_kernel(const float4* __restrict__ X,
    float4* __restrict__ xc, float4* __restrict__ prop, int n4) {
  int i = blockIdx.x * 256 + threadIdx.x;
  if (i >= n4) return;
  float4 v = X[i];
  v.x *= 0.5f; v.y *= 0.5f; v.z *= 0.5f; v.w *= 0.5f;
  xc[i] = v;
  prop[i] = v;
}

// gather-sum per dst node: 32 lanes/node, float2/lane, batch-of-4 prefetch.
// ACC: even rounds fold prop += x_in + x_out (odd rounds skip prop entirely).
template<bool ACC>
__global__ __launch_bounds__(256) void spmm_csr(const float2* __restrict__ x,
    const int* __restrict__ row_start, const int2* __restrict__ adj,
    float2* __restrict__ xn, float2* __restrict__ prop) {
  const int node = blockIdx.x * 8 + (threadIdx.x >> 5);   // 100000 % 8 == 0
  const int f2 = threadIdx.x & 31;
  const int beg = row_start[node];
  const int end = row_start[node + 1];
  const int nfull = (end - beg) >> 2;
  const size_t o = (size_t)node * 32 + f2;
  float2 xin;
  if (ACC) xin = x[o];   // own input row (coalesced), needed for prop pairing
  float2 a0 = make_float2(0.f, 0.f), a1 = a0;

  int2 e0, e1, e2, e3;
  float2 v0, v1, v2, v3;
  if (nfull > 0) {
    e0 = adj[beg];     e1 = adj[beg + 1]; e2 = adj[beg + 2]; e3 = adj[beg + 3];
    v0 = x[(size_t)e0.x * 32 + f2];
    v1 = x[(size_t)e1.x * 32 + f2];
    v2 = x[(size_t)e2.x * 32 + f2];
    v3 = x[(size_t)e3.x * 32 + f2];
  }
  for (int b = 1; b < nfull; ++b) {
    const int q = beg + 4 * b;
    int2 g0 = adj[q], g1 = adj[q + 1], g2 = adj[q + 2], g3 = adj[q + 3];
    float2 u0 = x[(size_t)g0.x * 32 + f2];
    float2 u1 = x[(size_t)g1.x * 32 + f2];
    float2 u2 = x[(size_t)g2.x * 32 + f2];
    float2 u3 = x[(size_t)g3.x * 32 + f2];
    float w0 = __int_as_float(e0.y), w1 = __int_as_float(e1.y);
    float w2 = __int_as_float(e2.y), w3 = __int_as_float(e3.y);
    a0.x = fmaf(v0.x, w0, a0.x); a0.y = fmaf(v0.y, w0, a0.y);
    a1.x = fmaf(v1.x, w1, a1.x); a1.y = fmaf(v1.y, w1, a1.y);
    a0.x = fmaf(v2.x, w2, a0.x); a0.y = fmaf(v2.y, w2, a0.y);
    a1.x = fmaf(v3.x, w3, a1.x); a1.y = fmaf(v3.y, w3, a1.y);
    e0 = g0; e1 = g1; e2 = g2; e3 = g3;
    v0 = u0; v1 = u1; v2 = u2; v3 = u3;
  }
  if (nfull > 0) {
    float w0 = __int_as_float(e0.y), w1 = __int_as_float(e1.y);
    float w2 = __int_as_float(e2.y), w3 = __int_as_float(e3.y);
    a0.x = fmaf(v0.x, w0, a0.x); a0.y = fmaf(v0.y, w0, a0.y);
    a1.x = fmaf(v1.x, w1, a1.x); a1.y = fmaf(v1.y, w1, a1.y);
    a0.x = fmaf(v2.x, w2, a0.x); a0.y = fmaf(v2.y, w2, a0.y);
    a1.x = fmaf(v3.x, w3, a1.x); a1.y = fmaf(v3.y, w3, a1.y);
  }
  for (int p = beg + 4 * nfull; p < end; ++p) {
    int2 e = adj[p];
    float2 v = x[(size_t)e.x * 32 + f2];
    float w = __int_as_float(e.y);
    a0.x = fmaf(v.x, w, a0.x); a0.y = fmaf(v.y, w, a0.y);
  }
  a0.x += a1.x; a0.y += a1.y;
  xn[o] = a0;
  if (ACC) {
    float2 pr = prop[o];
    pr.x += xin.x + a0.x;
    pr.y += xin.y + a0.y;
    prop[o] = pr;
  }
}

// ---------------- fused tail: fp16 h-staging, 21.6 KB LDS ----------------
// 32 nodes/block. Xp = normalize(prop/9); h = normalize(relu(Xp@W0+b0)); out = h@W1+b1.
struct H2x4 { __half2 a, b, c, d; };   // 8 halves = 16 B

__global__ __launch_bounds__(256, 6) void tail_kernel(
    const float* __restrict__ prop, const float* __restrict__ W0,
    const float* __restrict__ b0, const float* __restrict__ W1T,
    const float* __restrict__ b1, float* __restrict__ out) {
  // sHh[32][264] fp16 (16.9 KB); head bytes double as sXTn fp32[32][68] (8.7 KB)
  __shared__ __align__(16) __half sHh[32][264];
  __shared__ float sPart[32][36];
  __shared__ float sHinv[32];
  float (*sXTn)[68] = reinterpret_cast<float (*)[68]>(&sHh[0][0]);

  const int t = threadIdx.x;
  const int lane = t & 63;
  const int w = t >> 6;
  const int base = blockIdx.x * 32;   // 3125 * 32 == 100000 exactly

  // ---- load + Xp-normalize: wave handles one node per iter, node-major ----
  #pragma unroll
  for (int it = 0; it < 8; ++it) {
    const int nb = it * 4 + w;
    float v = prop[(size_t)(base + nb) * NF + lane];
    float ss = v * v;
    #pragma unroll
    for (int m = 1; m < 64; m <<= 1) ss += __shfl_xor(ss, m, 64);
    float nrm = sqrtf(ss) * (1.0f / 9.0f);
    float scale = (1.0f / 9.0f) / (1e-12f + nrm);
    sXTn[nb][lane] = v * scale;
  }
  __syncthreads();

  // ---- GEMM1: thread = 8 cols (8*tc..) x 4 nodes (tn, tn+8, tn+16, tn+24) ----
  const int tc = t >> 3;   // 0..31
  const int tn = t & 7;    // 0..7
  const float4* W0v = (const float4*)W0;
  float4 b0a = ((const float4*)b0)[2 * tc];
  float4 b0b = ((const float4*)b0)[2 * tc + 1];
  float acc[4][8];
  #pragma unroll
  for (int j = 0; j < 4; ++j) {
    acc[j][0] = b0a.x; acc[j][1] = b0a.y; acc[j][2] = b0a.z; acc[j][3] = b0a.w;
    acc[j][4] = b0b.x; acc[j][5] = b0b.y; acc[j][6] = b0b.z; acc[j][7] = b0b.w;
  }
  for (int k = 0; k < NF; k += 4) {
    float xsA[4], xsB[4], xsC[4], xsD[4];
    *(float4*)xsA = *(const float4*)&sXTn[tn][k];
    *(float4*)xsB = *(const float4*)&sXTn[tn + 8][k];
    *(float4*)xsC = *(const float4*)&sXTn[tn + 16][k];
    *(float4*)xsD = *(const float4*)&sXTn[tn + 24][k];
    #pragma unroll
    for (int kk = 0; kk < 4; ++kk) {
      float4 wa = W0v[(k + kk) * 64 + 2 * tc];
      float4 wb = W0v[(k + kk) * 64 + 2 * tc + 1];
      acc[0][0] = fmaf(xsA[kk], wa.x, acc[0][0]);
      acc[0][1] = fmaf(xsA[kk], wa.y, acc[0][1]);
      acc[0][2] = fmaf(xsA[kk], wa.z, acc[0][2]);
      acc[0][3] = fmaf(xsA[kk], wa.w, acc[0][3]);
      acc[0][4] = fmaf(xsA[kk], wb.x, acc[0][4]);
      acc[0][5] = fmaf(xsA[kk], wb.y, acc[0][5]);
      acc[0][6] = fmaf(xsA[kk], wb.z, acc[0][6]);
      acc[0][7] = fmaf(xsA[kk], wb.w, acc[0][7]);
      acc[1][0] = fmaf(xsB[kk], wa.x, acc[1][0]);
      acc[1][1] = fmaf(xsB[kk], wa.y, acc[1][1]);
      acc[1][2] = fmaf(xsB[kk], wa.z, acc[1][2]);
      acc[1][3] = fmaf(xsB[kk], wa.w, acc[1][3]);
      acc[1][4] = fmaf(xsB[kk], wb.x, acc[1][4]);
      acc[1][5] = fmaf(xsB[kk], wb.y, acc[1][5]);
      acc[1][6] = fmaf(xsB[kk], wb.z, acc[1][6]);
      acc[1][7] = fmaf(xsB[kk], wb.w, acc[1][7]);
      acc[2][0] = fmaf(xsC[kk], wa.x, acc[2][0]);
      acc[2][1] = fmaf(xsC[kk], wa.y, acc[2][1]);
      acc[2][2] = fmaf(xsC[kk], wa.z, acc[2][2]);
      acc[2][3] = fmaf(xsC[kk], wa.w, acc[2][3]);
      acc[2][4] = fmaf(xsC[kk], wb.x, acc[2][4]);
      acc[2][5] = fmaf(xsC[kk], wb.y, acc[2][5]);
      acc[2][6] = fmaf(xsC[kk], wb.z, acc[2][6]);
      acc[2][7] = fmaf(xsC[kk], wb.w, acc[2][7]);
      acc[3][0] = fmaf(xsD[kk], wa.x, acc[3][0]);
      acc[3][1] = fmaf(xsD[kk], wa.y, acc[3][1]);
      acc[3][2] = fmaf(xsD[kk], wa.z, acc[3][2]);
      acc[3][3] = fmaf(xsD[kk], wa.w, acc[3][3]);
      acc[3][4] = fmaf(xsD[kk], wb.x, acc[3][4]);
      acc[3][5] = fmaf(xsD[kk], wb.y, acc[3][5]);
      acc[3][6] = fmaf(xsD[kk], wb.z, acc[3][6]);
      acc[3][7] = fmaf(xsD[kk], wb.w, acc[3][7]);
    }
  }

  // relu + per-node partial sumsq
  #pragma unroll
  for (int j = 0; j < 4; ++j) {
    float part = 0.0f;
    #pragma unroll
    for (int i = 0; i < 8; ++i) {
      float a = fmaxf(acc[j][i], 0.0f);
      acc[j][i] = a;
      part = fmaf(a, a, part);
    }
    sPart[tn + 8 * j][tc] = part;
  }
  __syncthreads();

  if (t < 32) {
    float s = 0.0f;
    #pragma unroll
    for (int i = 0; i < 32; ++i) s += sPart[t][i];
    sHinv[t] = 1.0f / (1e-12f + sqrtf(s));
  }
  __syncthreads();

  // scale + store h as fp16 node-major (clobbers the dead sXTn alias region)
  #pragma unroll
  for (int j = 0; j < 4; ++j) {
    float sc = sHinv[tn + 8 * j];
    H2x4 hp;
    hp.a = __floats2half2_rn(acc[j][0] * sc, acc[j][1] * sc);
    hp.b = __floats2half2_rn(acc[j][2] * sc, acc[j][3] * sc);
    hp.c = __floats2half2_rn(acc[j][4] * sc, acc[j][5] * sc);
    hp.d = __floats2half2_rn(acc[j][6] * sc, acc[j][7] * sc);
    *(H2x4*)&sHh[tn + 8 * j][8 * tc] = hp;
  }
  __syncthreads();

  // ---- GEMM2: thread = 3 cols {tc2, tc2+16, tc2+32} x 2 nodes {tn2, tn2+16} ----
  const int tn2 = t & 15;
  const int tc2 = t >> 4;   // 0..15
  const bool c3 = (tc2 < 15);
  const float4* w1a = (const float4*)&W1T[tc2 * 256];
  const float4* w1b = (const float4*)&W1T[(tc2 + 16) * 256];
  const float4* w1c = (const float4*)&W1T[(c3 ? tc2 + 32 : tc2) * 256];
  float a00 = b1[tc2], a01 = b1[tc2 + 16], a02 = c3 ? b1[tc2 + 32] : 0.0f;
  float a10 = a00,     a11 = a01,          a12 = a02;
  for (int it = 0; it < 32; ++it) {       // 8 k per iter
    H2x4 h0p = *(const H2x4*)&sHh[tn2][8 * it];
    H2x4 h1p = *(const H2x4*)&sHh[tn2 + 16][8 * it];
    float2 h0a = __half22float2(h0p.a), h0b = __half22float2(h0p.b);
    float2 h0c = __half22float2(h0p.c), h0d = __half22float2(h0p.d);
    float2 h1a = __half22float2(h1p.a), h1b = __half22float2(h1p.b);
    float2 h1c = __half22float2(h1p.c), h1d = __half22float2(h1p.d);
    float4 wa0 = w1a[2 * it], wa1 = w1a[2 * it + 1];
    float4 wb0 = w1b[2 * it], wb1 = w1b[2 * it + 1];
    float4 wc0 = w1c[2 * it], wc1 = w1c[2 * it + 1];
    a00 = fmaf(h0a.x, wa0.x, a00); a00 = fmaf(h0a.y, wa0.y, a00);
    a00 = fmaf(h0b.x, wa0.z, a00); a00 = fmaf(h0b.y, wa0.w, a00);
    a00 = fmaf(h0c.x, wa1.x, a00); a00 = fmaf(h0c.y, wa1.y, a00);
    a00 = fmaf(h0d.x, wa1.z, a00); a00 = fmaf(h0d.y, wa1.w, a00);
    a01 = fmaf(h0a.x, wb0.x, a01); a01 = fmaf(h0a.y, wb0.y, a01);
    a01 = fmaf(h0b.x, wb0.z, a01); a01 = fmaf(h0b.y, wb0.w, a01);
    a01 = fmaf(h0c.x, wb1.x, a01); a01 = fmaf(h0c.y, wb1.y, a01);
    a01 = fmaf(h0d.x, wb1.z, a01); a01 = fmaf(h0d.y, wb1.w, a01);
    a02 = fmaf(h0a.x, wc0.x, a02); a02 = fmaf(h0a.y, wc0.y, a02);
    a02 = fmaf(h0b.x, wc0.z, a02); a02 = fmaf(h0b.y, wc0.w, a02);
    a02 = fmaf(h0c.x, wc1.x, a02); a02 = fmaf(h0c.y, wc1.y, a02);
    a02 = fmaf(h0d.x, wc1.z, a02); a02 = fmaf(h0d.y, wc1.w, a02);
    a10 = fmaf(h1a.x, wa0.x, a10); a10 = fmaf(h1a.y, wa0.y, a10);
    a10 = fmaf(h1b.x, wa0.z, a10); a10 = fmaf(h1b.y, wa0.w, a10);
    a10 = fmaf(h1c.x, wa1.x, a10); a10 = fmaf(h1c.y, wa1.y, a10);
    a10 = fmaf(h1d.x, wa1.z, a10); a10 = fmaf(h1d.y, wa1.w, a10);
    a11 = fmaf(h1a.x, wb0.x, a11); a11 = fmaf(h1a.y, wb0.y, a11);
    a11 = fmaf(h1b.x, wb0.z, a11); a11 = fmaf(h1b.y, wb0.w, a11);
    a11 = fmaf(h1c.x, wb1.x, a11); a11 = fmaf(h1c.y, wb1.y, a11);
    a11 = fmaf(h1d.x, wb1.z, a11); a11 = fmaf(h1d.y, wb1.w, a11);
    a12 = fmaf(h1a.x, wc0.x, a12); a12 = fmaf(h1a.y, wc0.y, a12);
    a12 = fmaf(h1b.x, wc0.z, a12); a12 = fmaf(h1b.y, wc0.w, a12);
    a12 = fmaf(h1c.x, wc1.x, a12); a12 = fmaf(h1c.y, wc1.y, a12);
    a12 = fmaf(h1d.x, wc1.z, a12); a12 = fmaf(h1d.y, wc1.w, a12);
  }
  {
    const size_t n0 = (size_t)(base + tn2) * 47;
    const size_t n1 = (size_t)(base + tn2 + 16) * 47;
    out[n0 + tc2] = a00;
    out[n0 + tc2 + 16] = a01;
    if (c3) out[n0 + tc2 + 32] = a02;
    out[n1 + tc2] = a10;
    out[n1 + tc2 + 16] = a11;
    if (c3) out[n1 + tc2 + 32] = a12;
  }
}

extern "C" void kernel_launch(void* const* d_in, const int* in_sizes, int n_in,
                              void* d_out, int out_size, void* d_ws, size_t ws_size,
                              hipStream_t stream) {
  (void)in_sizes; (void)n_in; (void)out_size; (void)ws_size;
  const float* X   = (const float*)d_in[0];
  const int*   src = (const int*)d_in[1];
  const int*   dst = (const int*)d_in[2];
  const float* ew  = (const float*)d_in[3];
  const float* W0  = (const float*)d_in[4];
  const float* b0  = (const float*)d_in[5];
  const float* W1  = (const float*)d_in[6];
  const float* b1  = (const float*)d_in[7];
  float* out = (float*)d_out;

  const size_t nf = (size_t)N_NODES * NF;
  float* bufA = (float*)d_ws;
  float* bufB = bufA + nf;
  float* prop = bufB + nf;
  int* counts     = (int*)(prop + nf);
  int* row_start  = counts + N_NODES;            // N_NODES+1
  int* cursor     = row_start + (N_NODES + 1);
  int* blockSums  = cursor + N_NODES;
  int* blockOffs  = blockSums + NBLK;
  float* W1T      = (float*)(((uintptr_t)(blockOffs + NBLK) + 15) & ~(uintptr_t)15);
  int2* adj       = (int2*)(((uintptr_t)(W1T + 47 * 256) + 15) & ~(uintptr_t)15);

  const int eblocks = (N_EDGES + 255) / 256;

  zero_ints<<<NBLK, 256, 0, stream>>>(counts, N_NODES);
  hist_kernel<<<eblocks, 256, 0, stream>>>(dst, counts);
  reduce_counts<<<NBLK, 256, 0, stream>>>(counts, blockSums);
  scan_partials<<<1, 512, 0, stream>>>(blockSums, blockOffs);
  scan_blocks<<<NBLK, 256, 0, stream>>>(counts, blockOffs, row_start, cursor);
  fill_kernel<<<eblocks, 256, 0, stream>>>(src, dst, ew, cursor, adj);
  transpose_w1<<<1, 256, 0, stream>>>(W1, W1T);

  const int n4 = (int)(nf / 4);
  init_kernel<<<(n4 + 255) / 256, 256, 0, stream>>>(
      (const float4*)X, (float4*)bufA, (float4*)prop, n4);

  float* xc = bufA;
  float* xn = bufB;
  for (int r = 0; r < ORDER; ++r) {
    if (r & 1) {
      spmm_csr<true><<<N_NODES / 8, 256, 0, stream>>>(
          (const float2*)xc, row_start, adj, (float2*)xn, (float2*)prop);
    } else {
      spmm_csr<false><<<N_NODES / 8, 256, 0, stream>>>(
          (const float2*)xc, row_start, adj, (float2*)xn, (float2*)prop);
    }
    float* tmp = xc; xc = xn; xn = tmp;
  }

  tail_kernel<<<N_NODES / 32, 256, 0, stream>>>(prop, W0, b0, W1T, b1, out);
}

// Round 9
// 648.976 us; speedup vs baseline: 1.5608x; 1.2993x over previous
//
#include <hip/hip_runtime.h>
#include <hip/hip_fp16.h>
#include <math.h>

#define N_NODES 100000
#define N_EDGES 1600000
#define NF 64
#define ORDER 8
#define NBLK 391          // ceil(N_NODES/256)

struct __align__(8) H4 { __half2 a, b; };   // 4 halves

// ---------------- CSR build (once per launch) ----------------

__global__ __launch_bounds__(256) void zero_ints(int* __restrict__ c, int n) {
  int i = blockIdx.x * 256 + threadIdx.x;
  if (i < n) c[i] = 0;
}

__global__ __launch_bounds__(256) void hist_kernel(const int* __restrict__ dst,
                                                   int* __restrict__ counts) {
  int e = blockIdx.x * 256 + threadIdx.x;
  if (e < N_EDGES) atomicAdd(&counts[dst[e]], 1);
}

__global__ __launch_bounds__(256) void reduce_counts(const int* __restrict__ counts,
                                                     int* __restrict__ blockSums) {
  int i = blockIdx.x * 256 + threadIdx.x;
  int v = (i < N_NODES) ? counts[i] : 0;
  #pragma unroll
  for (int m = 1; m < 64; m <<= 1) v += __shfl_xor(v, m, 64);
  __shared__ int s[4];
  if ((threadIdx.x & 63) == 0) s[threadIdx.x >> 6] = v;
  __syncthreads();
  if (threadIdx.x == 0) blockSums[blockIdx.x] = s[0] + s[1] + s[2] + s[3];
}

__global__ __launch_bounds__(512) void scan_partials(const int* __restrict__ blockSums,
                                                     int* __restrict__ blockOffs) {
  __shared__ int s[512];
  int t = threadIdx.x;
  int v = (t < NBLK) ? blockSums[t] : 0;
  s[t] = v;
  __syncthreads();
  for (int off = 1; off < 512; off <<= 1) {
    int u = (t >= off) ? s[t - off] : 0;
    __syncthreads();
    s[t] += u;
    __syncthreads();
  }
  if (t < NBLK) blockOffs[t] = s[t] - v;   // exclusive
}

__global__ __launch_bounds__(256) void scan_blocks(const int* __restrict__ counts,
    const int* __restrict__ blockOffs, int* __restrict__ row_start,
    int* __restrict__ cursor) {
  __shared__ int s[256];
  int t = threadIdx.x;
  int i = blockIdx.x * 256 + t;
  int v = (i < N_NODES) ? counts[i] : 0;
  s[t] = v;
  __syncthreads();
  for (int off = 1; off < 256; off <<= 1) {
    int u = (t >= off) ? s[t - off] : 0;
    __syncthreads();
    s[t] += u;
    __syncthreads();
  }
  int excl = s[t] - v + blockOffs[blockIdx.x];
  if (i < N_NODES) { row_start[i] = excl; cursor[i] = excl; }
  if (i == N_NODES - 1) row_start[N_NODES] = excl + v;
}

__global__ __launch_bounds__(256) void fill_kernel(const int* __restrict__ src,
    const int* __restrict__ dst, const float* __restrict__ ew,
    int* __restrict__ cursor, int2* __restrict__ adj) {
  int e = blockIdx.x * 256 + threadIdx.x;
  if (e >= N_EDGES) return;
  int d = dst[e];
  int pos = atomicAdd(&cursor[d], 1);
  adj[pos] = make_int2(src[e], __float_as_int(ew[e]));
}

// W1 [256][47] -> W1T [47][256]
__global__ __launch_bounds__(256) void transpose_w1(const float* __restrict__ W1,
                                                    float* __restrict__ W1T) {
  int k = threadIdx.x;
  for (int c = 0; c < 47; ++c) W1T[c * 256 + k] = W1[k * 47 + c];
}

// ---------------- propagation ----------------

// x_cur = fp16(X*0.5) ; prop = fp32(X*0.5)
__global__ __launch_bounds__(256) void init_kernel(const float4* __restrict__ X,
    H4* __restrict__ xc, float4* __restrict__ prop, int n4) {
  int i = blockIdx.x * 256 + threadIdx.x;
  if (i >= n4) return;
  float4 v = X[i];
  v.x *= 0.5f; v.y *= 0.5f; v.z *= 0.5f; v.w *= 0.5f;
  prop[i] = v;
  H4 h;
  h.a = __floats2half2_rn(v.x, v.y);
  h.b = __floats2half2_rn(v.z, v.w);
  xc[i] = h;
}

// gather-sum per dst node: 32 lanes/node, half2/lane (128 B per row gather),
// fp32 accumulate, batch-of-4 prefetch.
// ACC rounds fold prop += x_in + x_out (other rounds skip prop entirely).
template<bool ACC>
__global__ __launch_bounds__(256) void spmm_csr(const __half2* __restrict__ x,
    const int* __restrict__ row_start, const int2* __restrict__ adj,
    __half2* __restrict__ xn, float2* __restrict__ prop) {
  const int node = blockIdx.x * 8 + (threadIdx.x >> 5);   // 100000 % 8 == 0
  const int f2 = threadIdx.x & 31;
  const int beg = row_start[node];
  const int end = row_start[node + 1];
  const int nfull = (end - beg) >> 2;
  const size_t o = (size_t)node * 32 + f2;
  float2 xin;
  if (ACC) xin = __half22float2(x[o]);
  float2 a0 = make_float2(0.f, 0.f), a1 = a0;

  int2 e0, e1, e2, e3;
  __half2 v0, v1, v2, v3;
  if (nfull > 0) {
    e0 = adj[beg];     e1 = adj[beg + 1]; e2 = adj[beg + 2]; e3 = adj[beg + 3];
    v0 = x[(size_t)e0.x * 32 + f2];
    v1 = x[(size_t)e1.x * 32 + f2];
    v2 = x[(size_t)e2.x * 32 + f2];
    v3 = x[(size_t)e3.x * 32 + f2];
  }
  for (int b = 1; b < nfull; ++b) {
    const int q = beg + 4 * b;
    int2 g0 = adj[q], g1 = adj[q + 1], g2 = adj[q + 2], g3 = adj[q + 3];
    __half2 u0 = x[(size_t)g0.x * 32 + f2];
    __half2 u1 = x[(size_t)g1.x * 32 + f2];
    __half2 u2 = x[(size_t)g2.x * 32 + f2];
    __half2 u3 = x[(size_t)g3.x * 32 + f2];
    float2 f0 = __half22float2(v0), f1 = __half22float2(v1);
    float2 f2v = __half22float2(v2), f3 = __half22float2(v3);
    float w0 = __int_as_float(e0.y), w1 = __int_as_float(e1.y);
    float w2 = __int_as_float(e2.y), w3 = __int_as_float(e3.y);
    a0.x = fmaf(f0.x, w0, a0.x); a0.y = fmaf(f0.y, w0, a0.y);
    a1.x = fmaf(f1.x, w1, a1.x); a1.y = fmaf(f1.y, w1, a1.y);
    a0.x = fmaf(f2v.x, w2, a0.x); a0.y = fmaf(f2v.y, w2, a0.y);
    a1.x = fmaf(f3.x, w3, a1.x); a1.y = fmaf(f3.y, w3, a1.y);
    e0 = g0; e1 = g1; e2 = g2; e3 = g3;
    v0 = u0; v1 = u1; v2 = u2; v3 = u3;
  }
  if (nfull > 0) {
    float2 f0 = __half22float2(v0), f1 = __half22float2(v1);
    float2 f2v = __half22float2(v2), f3 = __half22float2(v3);
    float w0 = __int_as_float(e0.y), w1 = __int_as_float(e1.y);
    float w2 = __int_as_float(e2.y), w3 = __int_as_float(e3.y);
    a0.x = fmaf(f0.x, w0, a0.x); a0.y = fmaf(f0.y, w0, a0.y);
    a1.x = fmaf(f1.x, w1, a1.x); a1.y = fmaf(f1.y, w1, a1.y);
    a0.x = fmaf(f2v.x, w2, a0.x); a0.y = fmaf(f2v.y, w2, a0.y);
    a1.x = fmaf(f3.x, w3, a1.x); a1.y = fmaf(f3.y, w3, a1.y);
  }
  for (int p = beg + 4 * nfull; p < end; ++p) {
    int2 e = adj[p];
    float2 v = __half22float2(x[(size_t)e.x * 32 + f2]);
    float w = __int_as_float(e.y);
    a0.x = fmaf(v.x, w, a0.x); a0.y = fmaf(v.y, w, a0.y);
  }
  a0.x += a1.x; a0.y += a1.y;
  xn[o] = __floats2half2_rn(a0.x, a0.y);
  if (ACC) {
    float2 pr = prop[o];
    pr.x += xin.x + a0.x;
    pr.y += xin.y + a0.y;
    prop[o] = pr;
  }
}

// ---------------- fused tail: fp16 h-staging, 21.6 KB LDS ----------------
struct H2x4 { __half2 a, b, c, d; };   // 8 halves = 16 B

__global__ __launch_bounds__(256, 6) void tail_kernel(
    const float* __restrict__ prop, const float* __restrict__ W0,
    const float* __restrict__ b0, const float* __restrict__ W1T,
    const float* __restrict__ b1, float* __restrict__ out) {
  __shared__ __align__(16) __half sHh[32][264];
  __shared__ float sPart[32][36];
  __shared__ float sHinv[32];
  float (*sXTn)[68] = reinterpret_cast<float (*)[68]>(&sHh[0][0]);

  const int t = threadIdx.x;
  const int lane = t & 63;
  const int w = t >> 6;
  const int base = blockIdx.x * 32;   // 3125 * 32 == 100000 exactly

  #pragma unroll
  for (int it = 0; it < 8; ++it) {
    const int nb = it * 4 + w;
    float v = prop[(size_t)(base + nb) * NF + lane];
    float ss = v * v;
    #pragma unroll
    for (int m = 1; m < 64; m <<= 1) ss += __shfl_xor(ss, m, 64);
    float nrm = sqrtf(ss) * (1.0f / 9.0f);
    float scale = (1.0f / 9.0f) / (1e-12f + nrm);
    sXTn[nb][lane] = v * scale;
  }
  __syncthreads();

  const int tc = t >> 3;   // 0..31
  const int tn = t & 7;    // 0..7
  const float4* W0v = (const float4*)W0;
  float4 b0a = ((const float4*)b0)[2 * tc];
  float4 b0b = ((const float4*)b0)[2 * tc + 1];
  float acc[4][8];
  #pragma unroll
  for (int j = 0; j < 4; ++j) {
    acc[j][0] = b0a.x; acc[j][1] = b0a.y; acc[j][2] = b0a.z; acc[j][3] = b0a.w;
    acc[j][4] = b0b.x; acc[j][5] = b0b.y; acc[j][6] = b0b.z; acc[j][7] = b0b.w;
  }
  for (int k = 0; k < NF; k += 4) {
    float xsA[4], xsB[4], xsC[4], xsD[4];
    *(float4*)xsA = *(const float4*)&sXTn[tn][k];
    *(float4*)xsB = *(const float4*)&sXTn[tn + 8][k];
    *(float4*)xsC = *(const float4*)&sXTn[tn + 16][k];
    *(float4*)xsD = *(const float4*)&sXTn[tn + 24][k];
    #pragma unroll
    for (int kk = 0; kk < 4; ++kk) {
      float4 wa = W0v[(k + kk) * 64 + 2 * tc];
      float4 wb = W0v[(k + kk) * 64 + 2 * tc + 1];
      acc[0][0] = fmaf(xsA[kk], wa.x, acc[0][0]);
      acc[0][1] = fmaf(xsA[kk], wa.y, acc[0][1]);
      acc[0][2] = fmaf(xsA[kk], wa.z, acc[0][2]);
      acc[0][3] = fmaf(xsA[kk], wa.w, acc[0][3]);
      acc[0][4] = fmaf(xsA[kk], wb.x, acc[0][4]);
      acc[0][5] = fmaf(xsA[kk], wb.y, acc[0][5]);
      acc[0][6] = fmaf(xsA[kk], wb.z, acc[0][6]);
      acc[0][7] = fmaf(xsA[kk], wb.w, acc[0][7]);
      acc[1][0] = fmaf(xsB[kk], wa.x, acc[1][0]);
      acc[1][1] = fmaf(xsB[kk], wa.y, acc[1][1]);
      acc[1][2] = fmaf(xsB[kk], wa.z, acc[1][2]);
      acc[1][3] = fmaf(xsB[kk], wa.w, acc[1][3]);
      acc[1][4] = fmaf(xsB[kk], wb.x, acc[1][4]);
      acc[1][5] = fmaf(xsB[kk], wb.y, acc[1][5]);
      acc[1][6] = fmaf(xsB[kk], wb.z, acc[1][6]);
      acc[1][7] = fmaf(xsB[kk], wb.w, acc[1][7]);
      acc[2][0] = fmaf(xsC[kk], wa.x, acc[2][0]);
      acc[2][1] = fmaf(xsC[kk], wa.y, acc[2][1]);
      acc[2][2] = fmaf(xsC[kk], wa.z, acc[2][2]);
      acc[2][3] = fmaf(xsC[kk], wa.w, acc[2][3]);
      acc[2][4] = fmaf(xsC[kk], wb.x, acc[2][4]);
      acc[2][5] = fmaf(xsC[kk], wb.y, acc[2][5]);
      acc[2][6] = fmaf(xsC[kk], wb.z, acc[2][6]);
      acc[2][7] = fmaf(xsC[kk], wb.w, acc[2][7]);
      acc[3][0] = fmaf(xsD[kk], wa.x, acc[3][0]);
      acc[3][1] = fmaf(xsD[kk], wa.y, acc[3][1]);
      acc[3][2] = fmaf(xsD[kk], wa.z, acc[3][2]);
      acc[3][3] = fmaf(xsD[kk], wa.w, acc[3][3]);
      acc[3][4] = fmaf(xsD[kk], wb.x, acc[3][4]);
      acc[3][5] = fmaf(xsD[kk], wb.y, acc[3][5]);
      acc[3][6] = fmaf(xsD[kk], wb.z, acc[3][6]);
      acc[3][7] = fmaf(xsD[kk], wb.w, acc[3][7]);
    }
  }

  #pragma unroll
  for (int j = 0; j < 4; ++j) {
    float part = 0.0f;
    #pragma unroll
    for (int i = 0; i < 8; ++i) {
      float a = fmaxf(acc[j][i], 0.0f);
      acc[j][i] = a;
      part = fmaf(a, a, part);
    }
    sPart[tn + 8 * j][tc] = part;
  }
  __syncthreads();

  if (t < 32) {
    float s = 0.0f;
    #pragma unroll
    for (int i = 0; i < 32; ++i) s += sPart[t][i];
    sHinv[t] = 1.0f / (1e-12f + sqrtf(s));
  }
  __syncthreads();

  #pragma unroll
  for (int j = 0; j < 4; ++j) {
    float sc = sHinv[tn + 8 * j];
    H2x4 hp;
    hp.a = __floats2half2_rn(acc[j][0] * sc, acc[j][1] * sc);
    hp.b = __floats2half2_rn(acc[j][2] * sc, acc[j][3] * sc);
    hp.c = __floats2half2_rn(acc[j][4] * sc, acc[j][5] * sc);
    hp.d = __floats2half2_rn(acc[j][6] * sc, acc[j][7] * sc);
    *(H2x4*)&sHh[tn + 8 * j][8 * tc] = hp;
  }
  __syncthreads();

  const int tn2 = t & 15;
  const int tc2 = t >> 4;   // 0..15
  const bool c3 = (tc2 < 15);
  const float4* w1a = (const float4*)&W1T[tc2 * 256];
  const float4* w1b = (const float4*)&W1T[(tc2 + 16) * 256];
  const float4* w1c = (const float4*)&W1T[(c3 ? tc2 + 32 : tc2) * 256];
  float a00 = b1[tc2], a01 = b1[tc2 + 16], a02 = c3 ? b1[tc2 + 32] : 0.0f;
  float a10 = a00,     a11 = a01,          a12 = a02;
  for (int it = 0; it < 32; ++it) {       // 8 k per iter
    H2x4 h0p = *(const H2x4*)&sHh[tn2][8 * it];
    H2x4 h1p = *(const H2x4*)&sHh[tn2 + 16][8 * it];
    float2 h0a = __half22float2(h0p.a), h0b = __half22float2(h0p.b);
    float2 h0c = __half22float2(h0p.c), h0d = __half22float2(h0p.d);
    float2 h1a = __half22float2(h1p.a), h1b = __half22float2(h1p.b);
    float2 h1c = __half22float2(h1p.c), h1d = __half22float2(h1p.d);
    float4 wa0 = w1a[2 * it], wa1 = w1a[2 * it + 1];
    float4 wb0 = w1b[2 * it], wb1 = w1b[2 * it + 1];
    float4 wc0 = w1c[2 * it], wc1 = w1c[2 * it + 1];
    a00 = fmaf(h0a.x, wa0.x, a00); a00 = fmaf(h0a.y, wa0.y, a00);
    a00 = fmaf(h0b.x, wa0.z, a00); a00 = fmaf(h0b.y, wa0.w, a00);
    a00 = fmaf(h0c.x, wa1.x, a00); a00 = fmaf(h0c.y, wa1.y, a00);
    a00 = fmaf(h0d.x, wa1.z, a00); a00 = fmaf(h0d.y, wa1.w, a00);
    a01 = fmaf(h0a.x, wb0.x, a01); a01 = fmaf(h0a.y, wb0.y, a01);
    a01 = fmaf(h0b.x, wb0.z, a01); a01 = fmaf(h0b.y, wb0.w, a01);
    a01 = fmaf(h0c.x, wb1.x, a01); a01 = fmaf(h0c.y, wb1.y, a01);
    a01 = fmaf(h0d.x, wb1.z, a01); a01 = fmaf(h0d.y, wb1.w, a01);
    a02 = fmaf(h0a.x, wc0.x, a02); a02 = fmaf(h0a.y, wc0.y, a02);
    a02 = fmaf(h0b.x, wc0.z, a02); a02 = fmaf(h0b.y, wc0.w, a02);
    a02 = fmaf(h0c.x, wc1.x, a02); a02 = fmaf(h0c.y, wc1.y, a02);
    a02 = fmaf(h0d.x, wc1.z, a02); a02 = fmaf(h0d.y, wc1.w, a02);
    a10 = fmaf(h1a.x, wa0.x, a10); a10 = fmaf(h1a.y, wa0.y, a10);
    a10 = fmaf(h1b.x, wa0.z, a10); a10 = fmaf(h1b.y, wa0.w, a10);
    a10 = fmaf(h1c.x, wa1.x, a10); a10 = fmaf(h1c.y, wa1.y, a10);
    a10 = fmaf(h1d.x, wa1.z, a10); a10 = fmaf(h1d.y, wa1.w, a10);
    a11 = fmaf(h1a.x, wb0.x, a11); a11 = fmaf(h1a.y, wb0.y, a11);
    a11 = fmaf(h1b.x, wb0.z, a11); a11 = fmaf(h1b.y, wb0.w, a11);
    a11 = fmaf(h1c.x, wb1.x, a11); a11 = fmaf(h1c.y, wb1.y, a11);
    a11 = fmaf(h1d.x, wb1.z, a11); a11 = fmaf(h1d.y, wb1.w, a11);
    a12 = fmaf(h1a.x, wc0.x, a12); a12 = fmaf(h1a.y, wc0.y, a12);
    a12 = fmaf(h1b.x, wc0.z, a12); a12 = fmaf(h1b.y, wc0.w, a12);
    a12 = fmaf(h1c.x, wc1.x, a12); a12 = fmaf(h1c.y, wc1.y, a12);
    a12 = fmaf(h1d.x, wc1.z, a12); a12 = fmaf(h1d.y, wc1.w, a12);
  }
  {
    const size_t n0 = (size_t)(base + tn2) * 47;
    const size_t n1 = (size_t)(base + tn2 + 16) * 47;
    out[n0 + tc2] = a00;
    out[n0 + tc2 + 16] = a01;
    if (c3) out[n0 + tc2 + 32] = a02;
    out[n1 + tc2] = a10;
    out[n1 + tc2 + 16] = a11;
    if (c3) out[n1 + tc2 + 32] = a12;
  }
}

extern "C" void kernel_launch(void* const* d_in, const int* in_sizes, int n_in,
                              void* d_out, int out_size, void* d_ws, size_t ws_size,
                              hipStream_t stream) {
  (void)in_sizes; (void)n_in; (void)out_size; (void)ws_size;
  const float* X   = (const float*)d_in[0];
  const int*   src = (const int*)d_in[1];
  const int*   dst = (const int*)d_in[2];
  const float* ew  = (const float*)d_in[3];
  const float* W0  = (const float*)d_in[4];
  const float* b0  = (const float*)d_in[5];
  const float* W1  = (const float*)d_in[6];
  const float* b1  = (const float*)d_in[7];
  float* out = (float*)d_out;

  const size_t nf = (size_t)N_NODES * NF;    // 6.4M elements
  __half* bufA = (__half*)d_ws;              // 12.8 MB
  __half* bufB = bufA + nf;                  // 12.8 MB
  float*  prop = (float*)(bufB + nf);        // 25.6 MB
  int* counts     = (int*)(prop + nf);
  int* row_start  = counts + N_NODES;        // N_NODES+1
  int* cursor     = row_start + (N_NODES + 1);
  int* blockSums  = cursor + N_NODES;
  int* blockOffs  = blockSums + NBLK;
  float* W1T      = (float*)(((uintptr_t)(blockOffs + NBLK) + 15) & ~(uintptr_t)15);
  int2* adj       = (int2*)(((uintptr_t)(W1T + 47 * 256) + 15) & ~(uintptr_t)15);

  const int eblocks = (N_EDGES + 255) / 256;

  zero_ints<<<NBLK, 256, 0, stream>>>(counts, N_NODES);
  hist_kernel<<<eblocks, 256, 0, stream>>>(dst, counts);
  reduce_counts<<<NBLK, 256, 0, stream>>>(counts, blockSums);
  scan_partials<<<1, 512, 0, stream>>>(blockSums, blockOffs);
  scan_blocks<<<NBLK, 256, 0, stream>>>(counts, blockOffs, row_start, cursor);
  fill_kernel<<<eblocks, 256, 0, stream>>>(src, dst, ew, cursor, adj);
  transpose_w1<<<1, 256, 0, stream>>>(W1, W1T);

  const int n4 = (int)(nf / 4);
  init_kernel<<<(n4 + 255) / 256, 256, 0, stream>>>(
      (const float4*)X, (H4*)bufA, (float4*)prop, n4);

  __half* xc = bufA;
  __half* xn = bufB;
  for (int r = 0; r < ORDER; ++r) {
    if (r & 1) {
      spmm_csr<true><<<N_NODES / 8, 256, 0, stream>>>(
          (const __half2*)xc, row_start, adj, (__half2*)xn, (float2*)prop);
    } else {
      spmm_csr<false><<<N_NODES / 8, 256, 0, stream>>>(
          (const __half2*)xc, row_start, adj, (__half2*)xn, (float2*)prop);
    }
    __half* tmp = xc; xc = xn; xn = tmp;
  }

  tail_kernel<<<N_NODES / 32, 256, 0, stream>>>(prop, W0, b0, W1T, b1, out);
}

// Round 10
// 561.138 us; speedup vs baseline: 1.8052x; 1.1565x over previous
//
#include <hip/hip_runtime.h>
#include <hip/hip_fp16.h>
#include <math.h>

#define N_NODES 100000
#define N_EDGES 1600000
#define NF 64
#define ORDER 8
#define NBLK 391          // ceil(N_NODES/256)

struct __align__(8) H4 { __half2 a, b; };   // 4 halves

using f16x8 = __attribute__((ext_vector_type(8))) _Float16;
using f32x4 = __attribute__((ext_vector_type(4))) float;

// ---------------- CSR build (once per launch) ----------------

__global__ __launch_bounds__(256) void zero_ints(int* __restrict__ c, int n) {
  int i = blockIdx.x * 256 + threadIdx.x;
  if (i < n) c[i] = 0;
}

__global__ __launch_bounds__(256) void hist_kernel(const int* __restrict__ dst,
                                                   int* __restrict__ counts) {
  int e = blockIdx.x * 256 + threadIdx.x;
  if (e < N_EDGES) atomicAdd(&counts[dst[e]], 1);
}

__global__ __launch_bounds__(256) void reduce_counts(const int* __restrict__ counts,
                                                     int* __restrict__ blockSums) {
  int i = blockIdx.x * 256 + threadIdx.x;
  int v = (i < N_NODES) ? counts[i] : 0;
  #pragma unroll
  for (int m = 1; m < 64; m <<= 1) v += __shfl_xor(v, m, 64);
  __shared__ int s[4];
  if ((threadIdx.x & 63) == 0) s[threadIdx.x >> 6] = v;
  __syncthreads();
  if (threadIdx.x == 0) blockSums[blockIdx.x] = s[0] + s[1] + s[2] + s[3];
}

__global__ __launch_bounds__(512) void scan_partials(const int* __restrict__ blockSums,
                                                     int* __restrict__ blockOffs) {
  __shared__ int s[512];
  int t = threadIdx.x;
  int v = (t < NBLK) ? blockSums[t] : 0;
  s[t] = v;
  __syncthreads();
  for (int off = 1; off < 512; off <<= 1) {
    int u = (t >= off) ? s[t - off] : 0;
    __syncthreads();
    s[t] += u;
    __syncthreads();
  }
  if (t < NBLK) blockOffs[t] = s[t] - v;   // exclusive
}

__global__ __launch_bounds__(256) void scan_blocks(const int* __restrict__ counts,
    const int* __restrict__ blockOffs, int* __restrict__ row_start,
    int* __restrict__ cursor) {
  __shared__ int s[256];
  int t = threadIdx.x;
  int i = blockIdx.x * 256 + t;
  int v = (i < N_NODES) ? counts[i] : 0;
  s[t] = v;
  __syncthreads();
  for (int off = 1; off < 256; off <<= 1) {
    int u = (t >= off) ? s[t - off] : 0;
    __syncthreads();
    s[t] += u;
    __syncthreads();
  }
  int excl = s[t] - v + blockOffs[blockIdx.x];
  if (i < N_NODES) { row_start[i] = excl; cursor[i] = excl; }
  if (i == N_NODES - 1) row_start[N_NODES] = excl + v;
}

__global__ __launch_bounds__(256) void fill_kernel(const int* __restrict__ src,
    const int* __restrict__ dst, const float* __restrict__ ew,
    int* __restrict__ cursor, int2* __restrict__ adj) {
  int e = blockIdx.x * 256 + threadIdx.x;
  if (e >= N_EDGES) return;
  int d = dst[e];
  int pos = atomicAdd(&cursor[d], 1);
  adj[pos] = make_int2(src[e], __float_as_int(ew[e]));
}

// Pack weights fp16 transposed: W0Th[256 n][64 k] = W0[k][n]; W1Th[48 c][256 k] = W1[k][c]
__global__ __launch_bounds__(256) void pack_weights(const float* __restrict__ W0,
    const float* __restrict__ W1, _Float16* __restrict__ W0Th,
    _Float16* __restrict__ W1Th) {
  int t = threadIdx.x;   // one block of 256
  for (int k = 0; k < 64; ++k)
    W0Th[t * 64 + k] = (_Float16)W0[k * 256 + t];
  for (int c = 0; c < 48; ++c) {
    float v = (c < 47) ? W1[t * 47 + c] : 0.0f;
    W1Th[c * 256 + t] = (_Float16)v;
  }
}

// ---------------- propagation ----------------

// x_cur = fp16(X*0.5) ; prop = fp32(X*0.5)
__global__ __launch_bounds__(256) void init_kernel(const float4* __restrict__ X,
    H4* __restrict__ xc, float4* __restrict__ prop, int n4) {
  int i = blockIdx.x * 256 + threadIdx.x;
  if (i >= n4) return;
  float4 v = X[i];
  v.x *= 0.5f; v.y *= 0.5f; v.z *= 0.5f; v.w *= 0.5f;
  prop[i] = v;
  H4 h;
  h.a = __floats2half2_rn(v.x, v.y);
  h.b = __floats2half2_rn(v.z, v.w);
  xc[i] = h;
}

// gather-sum per dst node: 32 lanes/node, half2/lane (128 B per row gather),
// fp32 accumulate, batch-of-4 prefetch.
template<bool ACC>
__global__ __launch_bounds__(256) void spmm_csr(const __half2* __restrict__ x,
    const int* __restrict__ row_start, const int2* __restrict__ adj,
    __half2* __restrict__ xn, float2* __restrict__ prop) {
  const int node = blockIdx.x * 8 + (threadIdx.x >> 5);   // 100000 % 8 == 0
  const int f2 = threadIdx.x & 31;
  const int beg = row_start[node];
  const int end = row_start[node + 1];
  const int nfull = (end - beg) >> 2;
  const size_t o = (size_t)node * 32 + f2;
  float2 xin;
  if (ACC) xin = __half22float2(x[o]);
  float2 a0 = make_float2(0.f, 0.f), a1 = a0;

  int2 e0, e1, e2, e3;
  __half2 v0, v1, v2, v3;
  if (nfull > 0) {
    e0 = adj[beg];     e1 = adj[beg + 1]; e2 = adj[beg + 2]; e3 = adj[beg + 3];
    v0 = x[(size_t)e0.x * 32 + f2];
    v1 = x[(size_t)e1.x * 32 + f2];
    v2 = x[(size_t)e2.x * 32 + f2];
    v3 = x[(size_t)e3.x * 32 + f2];
  }
  for (int b = 1; b < nfull; ++b) {
    const int q = beg + 4 * b;
    int2 g0 = adj[q], g1 = adj[q + 1], g2 = adj[q + 2], g3 = adj[q + 3];
    __half2 u0 = x[(size_t)g0.x * 32 + f2];
    __half2 u1 = x[(size_t)g1.x * 32 + f2];
    __half2 u2 = x[(size_t)g2.x * 32 + f2];
    __half2 u3 = x[(size_t)g3.x * 32 + f2];
    float2 f0 = __half22float2(v0), f1 = __half22float2(v1);
    float2 f2v = __half22float2(v2), f3 = __half22float2(v3);
    float w0 = __int_as_float(e0.y), w1 = __int_as_float(e1.y);
    float w2 = __int_as_float(e2.y), w3 = __int_as_float(e3.y);
    a0.x = fmaf(f0.x, w0, a0.x); a0.y = fmaf(f0.y, w0, a0.y);
    a1.x = fmaf(f1.x, w1, a1.x); a1.y = fmaf(f1.y, w1, a1.y);
    a0.x = fmaf(f2v.x, w2, a0.x); a0.y = fmaf(f2v.y, w2, a0.y);
    a1.x = fmaf(f3.x, w3, a1.x); a1.y = fmaf(f3.y, w3, a1.y);
    e0 = g0; e1 = g1; e2 = g2; e3 = g3;
    v0 = u0; v1 = u1; v2 = u2; v3 = u3;
  }
  if (nfull > 0) {
    float2 f0 = __half22float2(v0), f1 = __half22float2(v1);
    float2 f2v = __half22float2(v2), f3 = __half22float2(v3);
    float w0 = __int_as_float(e0.y), w1 = __int_as_float(e1.y);
    float w2 = __int_as_float(e2.y), w3 = __int_as_float(e3.y);
    a0.x = fmaf(f0.x, w0, a0.x); a0.y = fmaf(f0.y, w0, a0.y);
    a1.x = fmaf(f1.x, w1, a1.x); a1.y = fmaf(f1.y, w1, a1.y);
    a0.x = fmaf(f2v.x, w2, a0.x); a0.y = fmaf(f2v.y, w2, a0.y);
    a1.x = fmaf(f3.x, w3, a1.x); a1.y = fmaf(f3.y, w3, a1.y);
  }
  for (int p = beg + 4 * nfull; p < end; ++p) {
    int2 e = adj[p];
    float2 v = __half22float2(x[(size_t)e.x * 32 + f2]);
    float w = __int_as_float(e.y);
    a0.x = fmaf(v.x, w, a0.x); a0.y = fmaf(v.y, w, a0.y);
  }
  a0.x += a1.x; a0.y += a1.y;
  xn[o] = __floats2half2_rn(a0.x, a0.y);
  if (ACC) {
    float2 pr = prop[o];
    pr.x += xin.x + a0.x;
    pr.y += xin.y + a0.y;
    prop[o] = pr;
  }
}

// ---------------- fused tail, MFMA fp16 ----------------
// 32 nodes/block, 4 waves. Xp = normalize(prop/9) -> fp16 LDS;
// GEMM1 (32x64x256) + relu + norm -> fp16 LDS; GEMM2 (32x256x47).
// MFMA 16x16x32_f16. A: row=lane&15, k=(lane>>4)*8+0..7 (contig).
// B: col=lane&15 (row of W^T), same k. C/D: col=lane&15, row=(lane>>4)*4+reg.
__global__ __launch_bounds__(256) void tail_kernel(
    const float* __restrict__ prop, const float* __restrict__ b0,
    const _Float16* __restrict__ W0Th, const _Float16* __restrict__ W1Th,
    const float* __restrict__ b1, float* __restrict__ out) {
  __shared__ __align__(16) _Float16 sXp[32][72];    // 4.6 KB (row = 144 B, 16B-mult)
  __shared__ __align__(16) _Float16 sH[32][264];    // 16.9 KB (row = 528 B, 16B-mult)
  __shared__ float sPart[32][8];
  __shared__ float sHinv[32];

  const int t = threadIdx.x;
  const int lane = t & 63;
  const int w = t >> 6;
  const int l15 = lane & 15;
  const int l4 = lane >> 4;
  const int base = blockIdx.x * 32;   // 3125 * 32 == 100000 exactly

  // ---- load + Xp-normalize: wave handles one node per iter ----
  #pragma unroll
  for (int it = 0; it < 8; ++it) {
    const int nb = it * 4 + w;
    float v = prop[(size_t)(base + nb) * NF + lane];
    float ss = v * v;
    #pragma unroll
    for (int m = 1; m < 64; m <<= 1) ss += __shfl_xor(ss, m, 64);
    float nrm = sqrtf(ss) * (1.0f / 9.0f);
    float scale = (1.0f / 9.0f) / (1e-12f + nrm);
    sXp[nb][lane] = (_Float16)(v * scale);
  }
  __syncthreads();

  // ---- GEMM1: wave w owns n-tiles w*4..w*4+3; both m-tiles ----
  f32x4 acc1[2][4];
  #pragma unroll
  for (int j = 0; j < 4; ++j) {
    float bv = b0[(w * 4 + j) * 16 + l15];
    #pragma unroll
    for (int mt = 0; mt < 2; ++mt)
      acc1[mt][j] = (f32x4){bv, bv, bv, bv};
  }
  #pragma unroll
  for (int ks = 0; ks < 2; ++ks) {
    const int koff = l4 * 8 + ks * 32;
    f16x8 a0 = *(const f16x8*)&sXp[l15][koff];
    f16x8 a1 = *(const f16x8*)&sXp[16 + l15][koff];
    #pragma unroll
    for (int j = 0; j < 4; ++j) {
      f16x8 b = *(const f16x8*)&W0Th[(size_t)((w * 4 + j) * 16 + l15) * 64 + koff];
      acc1[0][j] = __builtin_amdgcn_mfma_f32_16x16x32_f16(a0, b, acc1[0][j], 0, 0, 0);
      acc1[1][j] = __builtin_amdgcn_mfma_f32_16x16x32_f16(a1, b, acc1[1][j], 0, 0, 0);
    }
  }

  // ---- relu + per-(node,wave) sumsq partial ----
  #pragma unroll
  for (int mt = 0; mt < 2; ++mt) {
    #pragma unroll
    for (int r = 0; r < 4; ++r) {
      float s = 0.0f;
      #pragma unroll
      for (int j = 0; j < 4; ++j) {
        float x = fmaxf(acc1[mt][j][r], 0.0f);
        acc1[mt][j][r] = x;
        s = fmaf(x, x, s);
      }
      #pragma unroll
      for (int m = 1; m < 16; m <<= 1) s += __shfl_xor(s, m, 64);
      if (l15 == 0) sPart[mt * 16 + l4 * 4 + r][w] = s;
    }
  }
  __syncthreads();

  if (t < 32) {
    float s = sPart[t][0] + sPart[t][1] + sPart[t][2] + sPart[t][3];
    sHinv[t] = 1.0f / (1e-12f + sqrtf(s));
  }
  __syncthreads();

  // ---- scale + store h fp16 ----
  #pragma unroll
  for (int mt = 0; mt < 2; ++mt) {
    #pragma unroll
    for (int r = 0; r < 4; ++r) {
      const int row = mt * 16 + l4 * 4 + r;
      const float sc = sHinv[row];
      #pragma unroll
      for (int j = 0; j < 4; ++j)
        sH[row][(w * 4 + j) * 16 + l15] = (_Float16)(acc1[mt][j][r] * sc);
    }
  }
  __syncthreads();

  // ---- GEMM2: waves 0..2 each own one 16-col tile of the 48 (47 real) ----
  if (w < 3) {
    const int c = w * 16 + l15;
    float bv = (c < 47) ? b1[c] : 0.0f;
    f32x4 acc2[2];
    acc2[0] = (f32x4){bv, bv, bv, bv};
    acc2[1] = (f32x4){bv, bv, bv, bv};
    #pragma unroll
    for (int ks = 0; ks < 8; ++ks) {
      const int koff = l4 * 8 + ks * 32;
      f16x8 b = *(const f16x8*)&W1Th[(size_t)(w * 16 + l15) * 256 + koff];
      f16x8 a0 = *(const f16x8*)&sH[l15][koff];
      f16x8 a1 = *(const f16x8*)&sH[16 + l15][koff];
      acc2[0] = __builtin_amdgcn_mfma_f32_16x16x32_f16(a0, b, acc2[0], 0, 0, 0);
      acc2[1] = __builtin_amdgcn_mfma_f32_16x16x32_f16(a1, b, acc2[1], 0, 0, 0);
    }
    if (c < 47) {
      #pragma unroll
      for (int mt = 0; mt < 2; ++mt) {
        #pragma unroll
        for (int r = 0; r < 4; ++r) {
          const int node = base + mt * 16 + l4 * 4 + r;
          out[(size_t)node * 47 + c] = acc2[mt][r];
        }
      }
    }
  }
}

extern "C" void kernel_launch(void* const* d_in, const int* in_sizes, int n_in,
                              void* d_out, int out_size, void* d_ws, size_t ws_size,
                              hipStream_t stream) {
  (void)in_sizes; (void)n_in; (void)out_size; (void)ws_size;
  const float* X   = (const float*)d_in[0];
  const int*   src = (const int*)d_in[1];
  const int*   dst = (const int*)d_in[2];
  const float* ew  = (const float*)d_in[3];
  const float* W0  = (const float*)d_in[4];
  const float* b0  = (const float*)d_in[5];
  const float* W1  = (const float*)d_in[6];
  const float* b1  = (const float*)d_in[7];
  float* out = (float*)d_out;

  const size_t nf = (size_t)N_NODES * NF;    // 6.4M elements
  __half* bufA = (__half*)d_ws;              // 12.8 MB
  __half* bufB = bufA + nf;                  // 12.8 MB
  float*  prop = (float*)(bufB + nf);        // 25.6 MB
  int* counts     = (int*)(prop + nf);
  int* row_start  = counts + N_NODES;        // N_NODES+1
  int* cursor     = row_start + (N_NODES + 1);
  int* blockSums  = cursor + N_NODES;
  int* blockOffs  = blockSums + NBLK;
  _Float16* W0Th  = (_Float16*)(((uintptr_t)(blockOffs + NBLK) + 15) & ~(uintptr_t)15);
  _Float16* W1Th  = W0Th + 256 * 64;
  int2* adj       = (int2*)(((uintptr_t)(W1Th + 48 * 256) + 15) & ~(uintptr_t)15);

  const int eblocks = (N_EDGES + 255) / 256;

  zero_ints<<<NBLK, 256, 0, stream>>>(counts, N_NODES);
  hist_kernel<<<eblocks, 256, 0, stream>>>(dst, counts);
  reduce_counts<<<NBLK, 256, 0, stream>>>(counts, blockSums);
  scan_partials<<<1, 512, 0, stream>>>(blockSums, blockOffs);
  scan_blocks<<<NBLK, 256, 0, stream>>>(counts, blockOffs, row_start, cursor);
  fill_kernel<<<eblocks, 256, 0, stream>>>(src, dst, ew, cursor, adj);
  pack_weights<<<1, 256, 0, stream>>>(W0, W1, W0Th, W1Th);

  const int n4 = (int)(nf / 4);
  init_kernel<<<(n4 + 255) / 256, 256, 0, stream>>>(
      (const float4*)X, (H4*)bufA, (float4*)prop, n4);

  __half* xc = bufA;
  __half* xn = bufB;
  for (int r = 0; r < ORDER; ++r) {
    if (r & 1) {
      spmm_csr<true><<<N_NODES / 8, 256, 0, stream>>>(
          (const __half2*)xc, row_start, adj, (__half2*)xn, (float2*)prop);
    } else {
      spmm_csr<false><<<N_NODES / 8, 256, 0, stream>>>(
          (const __half2*)xc, row_start, adj, (__half2*)xn, (float2*)prop);
    }
    __half* tmp = xc; xc = xn; xn = tmp;
  }

  tail_kernel<<<N_NODES / 32, 256, 0, stream>>>(prop, b0, W0Th, W1Th, b1, out);
}

// Round 11
// 505.133 us; speedup vs baseline: 2.0053x; 1.1109x over previous
//
#include <hip/hip_runtime.h>
#include <hip/hip_fp16.h>
#include <math.h>

#define N_NODES 100000
#define N_EDGES 1600000
#define NF 64
#define ORDER 8
#define NBLK 391          // ceil(N_NODES/256)
#define MAX_ADJ (N_EDGES + 8 * N_NODES)   // padded upper bound

struct __align__(8) H4 { __half2 a, b; };   // 4 halves

using f16x8 = __attribute__((ext_vector_type(8))) _Float16;
using f32x4 = __attribute__((ext_vector_type(4))) float;

// ---------------- CSR build (once per launch) ----------------

__global__ __launch_bounds__(256) void zero_ints(int* __restrict__ c, int n) {
  int i = blockIdx.x * 256 + threadIdx.x;
  if (i < n) c[i] = 0;
}

__global__ __launch_bounds__(256) void hist_kernel(const int* __restrict__ dst,
                                                   int* __restrict__ counts) {
  int e = blockIdx.x * 256 + threadIdx.x;
  if (e < N_EDGES) atomicAdd(&counts[dst[e]], 1);
}

// padded count: round deg up to multiple of 8 (uniform PF=8 spmm loop)
__device__ __forceinline__ int padc(int c) { return (c + 7) & ~7; }

__global__ __launch_bounds__(256) void reduce_counts(const int* __restrict__ counts,
                                                     int* __restrict__ blockSums) {
  int i = blockIdx.x * 256 + threadIdx.x;
  int v = (i < N_NODES) ? padc(counts[i]) : 0;
  #pragma unroll
  for (int m = 1; m < 64; m <<= 1) v += __shfl_xor(v, m, 64);
  __shared__ int s[4];
  if ((threadIdx.x & 63) == 0) s[threadIdx.x >> 6] = v;
  __syncthreads();
  if (threadIdx.x == 0) blockSums[blockIdx.x] = s[0] + s[1] + s[2] + s[3];
}

__global__ __launch_bounds__(512) void scan_partials(const int* __restrict__ blockSums,
                                                     int* __restrict__ blockOffs) {
  __shared__ int s[512];
  int t = threadIdx.x;
  int v = (t < NBLK) ? blockSums[t] : 0;
  s[t] = v;
  __syncthreads();
  for (int off = 1; off < 512; off <<= 1) {
    int u = (t >= off) ? s[t - off] : 0;
    __syncthreads();
    s[t] += u;
    __syncthreads();
  }
  if (t < NBLK) blockOffs[t] = s[t] - v;   // exclusive
}

__global__ __launch_bounds__(256) void scan_blocks(const int* __restrict__ counts,
    const int* __restrict__ blockOffs, int* __restrict__ row_start,
    int* __restrict__ cursor) {
  __shared__ int s[256];
  int t = threadIdx.x;
  int i = blockIdx.x * 256 + t;
  int v = (i < N_NODES) ? padc(counts[i]) : 0;
  s[t] = v;
  __syncthreads();
  for (int off = 1; off < 256; off <<= 1) {
    int u = (t >= off) ? s[t - off] : 0;
    __syncthreads();
    s[t] += u;
    __syncthreads();
  }
  int excl = s[t] - v + blockOffs[blockIdx.x];
  if (i < N_NODES) { row_start[i] = excl; cursor[i] = excl; }
  if (i == N_NODES - 1) row_start[N_NODES] = excl + v;
}

// packed adj entry: src (17 bits) << 15 | weight as 15-bit fixed point.
// pad entries are 0 (src=0, w=0) via memset before fill.
__global__ __launch_bounds__(256) void fill_kernel(const int* __restrict__ src,
    const int* __restrict__ dst, const float* __restrict__ ew,
    int* __restrict__ cursor, unsigned int* __restrict__ adj) {
  int e = blockIdx.x * 256 + threadIdx.x;
  if (e >= N_EDGES) return;
  int d = dst[e];
  int pos = atomicAdd(&cursor[d], 1);
  unsigned int w15 = (unsigned int)rintf(ew[e] * 32767.0f);
  adj[pos] = ((unsigned int)src[e] << 15) | w15;
}

// Pack weights fp16 transposed: W0Th[256 n][64 k] = W0[k][n]; W1Th[48 c][256 k] = W1[k][c]
__global__ __launch_bounds__(256) void pack_weights(const float* __restrict__ W0,
    const float* __restrict__ W1, _Float16* __restrict__ W0Th,
    _Float16* __restrict__ W1Th) {
  int t = threadIdx.x;   // one block of 256
  for (int k = 0; k < 64; ++k)
    W0Th[t * 64 + k] = (_Float16)W0[k * 256 + t];
  for (int c = 0; c < 48; ++c) {
    float v = (c < 47) ? W1[t * 47 + c] : 0.0f;
    W1Th[c * 256 + t] = (_Float16)v;
  }
}

// ---------------- propagation ----------------

// x_cur = fp16(X*0.5) ; prop = fp32(X*0.5)
__global__ __launch_bounds__(256) void init_kernel(const float4* __restrict__ X,
    H4* __restrict__ xc, float4* __restrict__ prop, int n4) {
  int i = blockIdx.x * 256 + threadIdx.x;
  if (i >= n4) return;
  float4 v = X[i];
  v.x *= 0.5f; v.y *= 0.5f; v.z *= 0.5f; v.w *= 0.5f;
  prop[i] = v;
  H4 h;
  h.a = __floats2half2_rn(v.x, v.y);
  h.b = __floats2half2_rn(v.z, v.w);
  xc[i] = h;
}

// gather-sum per dst node: 32 lanes/node, half2/lane, fp32 accumulate.
// Rows padded to 8 -> uniform software-pipelined batch-of-8 (8 gathers in flight).
template<bool ACC>
__global__ __launch_bounds__(256) void spmm_csr(const __half2* __restrict__ x,
    const int* __restrict__ row_start, const unsigned int* __restrict__ adj,
    __half2* __restrict__ xn, float2* __restrict__ prop) {
  const int node = blockIdx.x * 8 + (threadIdx.x >> 5);   // 100000 % 8 == 0
  const int f2 = threadIdx.x & 31;
  const int beg = row_start[node];
  const int nb = (row_start[node + 1] - beg) >> 3;
  const size_t o = (size_t)node * 32 + f2;
  float2 xin;
  if (ACC) xin = __half22float2(x[o]);
  float2 a0 = make_float2(0.f, 0.f), a1 = a0;

  unsigned int e[8];
  __half2 v[8];
  if (nb > 0) {
    #pragma unroll
    for (int j = 0; j < 8; ++j) e[j] = adj[beg + j];
    #pragma unroll
    for (int j = 0; j < 8; ++j) v[j] = x[(size_t)(e[j] >> 15) * 32 + f2];
  }
  for (int b = 1; b < nb; ++b) {
    const int q = beg + 8 * b;
    unsigned int ne[8];
    __half2 nv[8];
    #pragma unroll
    for (int j = 0; j < 8; ++j) ne[j] = adj[q + j];
    #pragma unroll
    for (int j = 0; j < 8; ++j) nv[j] = x[(size_t)(ne[j] >> 15) * 32 + f2];
    #pragma unroll
    for (int j = 0; j < 8; ++j) {
      float w = (float)(e[j] & 0x7fffu) * (1.0f / 32767.0f);
      float2 f = __half22float2(v[j]);
      if (j & 1) { a1.x = fmaf(f.x, w, a1.x); a1.y = fmaf(f.y, w, a1.y); }
      else       { a0.x = fmaf(f.x, w, a0.x); a0.y = fmaf(f.y, w, a0.y); }
    }
    #pragma unroll
    for (int j = 0; j < 8; ++j) { e[j] = ne[j]; v[j] = nv[j]; }
  }
  if (nb > 0) {
    #pragma unroll
    for (int j = 0; j < 8; ++j) {
      float w = (float)(e[j] & 0x7fffu) * (1.0f / 32767.0f);
      float2 f = __half22float2(v[j]);
      if (j & 1) { a1.x = fmaf(f.x, w, a1.x); a1.y = fmaf(f.y, w, a1.y); }
      else       { a0.x = fmaf(f.x, w, a0.x); a0.y = fmaf(f.y, w, a0.y); }
    }
  }
  a0.x += a1.x; a0.y += a1.y;
  xn[o] = __floats2half2_rn(a0.x, a0.y);
  if (ACC) {
    float2 pr = prop[o];
    pr.x += xin.x + a0.x;
    pr.y += xin.y + a0.y;
    prop[o] = pr;
  }
}

// ---------------- fused tail, MFMA fp16 (unchanged from R10) ----------------
__global__ __launch_bounds__(256) void tail_kernel(
    const float* __restrict__ prop, const float* __restrict__ b0,
    const _Float16* __restrict__ W0Th, const _Float16* __restrict__ W1Th,
    const float* __restrict__ b1, float* __restrict__ out) {
  __shared__ __align__(16) _Float16 sXp[32][72];
  __shared__ __align__(16) _Float16 sH[32][264];
  __shared__ float sPart[32][8];
  __shared__ float sHinv[32];

  const int t = threadIdx.x;
  const int lane = t & 63;
  const int w = t >> 6;
  const int l15 = lane & 15;
  const int l4 = lane >> 4;
  const int base = blockIdx.x * 32;   // 3125 * 32 == 100000 exactly

  #pragma unroll
  for (int it = 0; it < 8; ++it) {
    const int nb = it * 4 + w;
    float v = prop[(size_t)(base + nb) * NF + lane];
    float ss = v * v;
    #pragma unroll
    for (int m = 1; m < 64; m <<= 1) ss += __shfl_xor(ss, m, 64);
    float nrm = sqrtf(ss) * (1.0f / 9.0f);
    float scale = (1.0f / 9.0f) / (1e-12f + nrm);
    sXp[nb][lane] = (_Float16)(v * scale);
  }
  __syncthreads();

  f32x4 acc1[2][4];
  #pragma unroll
  for (int j = 0; j < 4; ++j) {
    float bv = b0[(w * 4 + j) * 16 + l15];
    #pragma unroll
    for (int mt = 0; mt < 2; ++mt)
      acc1[mt][j] = (f32x4){bv, bv, bv, bv};
  }
  #pragma unroll
  for (int ks = 0; ks < 2; ++ks) {
    const int koff = l4 * 8 + ks * 32;
    f16x8 a0 = *(const f16x8*)&sXp[l15][koff];
    f16x8 a1 = *(const f16x8*)&sXp[16 + l15][koff];
    #pragma unroll
    for (int j = 0; j < 4; ++j) {
      f16x8 b = *(const f16x8*)&W0Th[(size_t)((w * 4 + j) * 16 + l15) * 64 + koff];
      acc1[0][j] = __builtin_amdgcn_mfma_f32_16x16x32_f16(a0, b, acc1[0][j], 0, 0, 0);
      acc1[1][j] = __builtin_amdgcn_mfma_f32_16x16x32_f16(a1, b, acc1[1][j], 0, 0, 0);
    }
  }

  #pragma unroll
  for (int mt = 0; mt < 2; ++mt) {
    #pragma unroll
    for (int r = 0; r < 4; ++r) {
      float s = 0.0f;
      #pragma unroll
      for (int j = 0; j < 4; ++j) {
        float x = fmaxf(acc1[mt][j][r], 0.0f);
        acc1[mt][j][r] = x;
        s = fmaf(x, x, s);
      }
      #pragma unroll
      for (int m = 1; m < 16; m <<= 1) s += __shfl_xor(s, m, 64);
      if (l15 == 0) sPart[mt * 16 + l4 * 4 + r][w] = s;
    }
  }
  __syncthreads();

  if (t < 32) {
    float s = sPart[t][0] + sPart[t][1] + sPart[t][2] + sPart[t][3];
    sHinv[t] = 1.0f / (1e-12f + sqrtf(s));
  }
  __syncthreads();

  #pragma unroll
  for (int mt = 0; mt < 2; ++mt) {
    #pragma unroll
    for (int r = 0; r < 4; ++r) {
      const int row = mt * 16 + l4 * 4 + r;
      const float sc = sHinv[row];
      #pragma unroll
      for (int j = 0; j < 4; ++j)
        sH[row][(w * 4 + j) * 16 + l15] = (_Float16)(acc1[mt][j][r] * sc);
    }
  }
  __syncthreads();

  if (w < 3) {
    const int c = w * 16 + l15;
    float bv = (c < 47) ? b1[c] : 0.0f;
    f32x4 acc2[2];
    acc2[0] = (f32x4){bv, bv, bv, bv};
    acc2[1] = (f32x4){bv, bv, bv, bv};
    #pragma unroll
    for (int ks = 0; ks < 8; ++ks) {
      const int koff = l4 * 8 + ks * 32;
      f16x8 b = *(const f16x8*)&W1Th[(size_t)(w * 16 + l15) * 256 + koff];
      f16x8 a0 = *(const f16x8*)&sH[l15][koff];
      f16x8 a1 = *(const f16x8*)&sH[16 + l15][koff];
      acc2[0] = __builtin_amdgcn_mfma_f32_16x16x32_f16(a0, b, acc2[0], 0, 0, 0);
      acc2[1] = __builtin_amdgcn_mfma_f32_16x16x32_f16(a1, b, acc2[1], 0, 0, 0);
    }
    if (c < 47) {
      #pragma unroll
      for (int mt = 0; mt < 2; ++mt) {
        #pragma unroll
        for (int r = 0; r < 4; ++r) {
          const int node = base + mt * 16 + l4 * 4 + r;
          out[(size_t)node * 47 + c] = acc2[mt][r];
        }
      }
    }
  }
}

extern "C" void kernel_launch(void* const* d_in, const int* in_sizes, int n_in,
                              void* d_out, int out_size, void* d_ws, size_t ws_size,
                              hipStream_t stream) {
  (void)in_sizes; (void)n_in; (void)out_size; (void)ws_size;
  const float* X   = (const float*)d_in[0];
  const int*   src = (const int*)d_in[1];
  const int*   dst = (const int*)d_in[2];
  const float* ew  = (const float*)d_in[3];
  const float* W0  = (const float*)d_in[4];
  const float* b0  = (const float*)d_in[5];
  const float* W1  = (const float*)d_in[6];
  const float* b1  = (const float*)d_in[7];
  float* out = (float*)d_out;

  const size_t nf = (size_t)N_NODES * NF;    // 6.4M elements
  __half* bufA = (__half*)d_ws;              // 12.8 MB
  __half* bufB = bufA + nf;                  // 12.8 MB
  float*  prop = (float*)(bufB + nf);        // 25.6 MB
  int* counts     = (int*)(prop + nf);
  int* row_start  = counts + N_NODES;        // N_NODES+1
  int* cursor     = row_start + (N_NODES + 1);
  int* blockSums  = cursor + N_NODES;
  int* blockOffs  = blockSums + NBLK;
  _Float16* W0Th  = (_Float16*)(((uintptr_t)(blockOffs + NBLK) + 15) & ~(uintptr_t)15);
  _Float16* W1Th  = W0Th + 256 * 64;
  unsigned int* adj = (unsigned int*)(((uintptr_t)(W1Th + 48 * 256) + 15) & ~(uintptr_t)15);

  const int eblocks = (N_EDGES + 255) / 256;

  zero_ints<<<NBLK, 256, 0, stream>>>(counts, N_NODES);
  hipMemsetAsync(adj, 0, (size_t)MAX_ADJ * 4, stream);   // pad entries = (src 0, w 0)
  hist_kernel<<<eblocks, 256, 0, stream>>>(dst, counts);
  reduce_counts<<<NBLK, 256, 0, stream>>>(counts, blockSums);
  scan_partials<<<1, 512, 0, stream>>>(blockSums, blockOffs);
  scan_blocks<<<NBLK, 256, 0, stream>>>(counts, blockOffs, row_start, cursor);
  fill_kernel<<<eblocks, 256, 0, stream>>>(src, dst, ew, cursor, adj);
  pack_weights<<<1, 256, 0, stream>>>(W0, W1, W0Th, W1Th);

  const int n4 = (int)(nf / 4);
  init_kernel<<<(n4 + 255) / 256, 256, 0, stream>>>(
      (const float4*)X, (H4*)bufA, (float4*)prop, n4);

  __half* xc = bufA;
  __half* xn = bufB;
  for (int r = 0; r < ORDER; ++r) {
    if (r & 1) {
      spmm_csr<true><<<N_NODES / 8, 256, 0, stream>>>(
          (const __half2*)xc, row_start, adj, (__half2*)xn, (float2*)prop);
    } else {
      spmm_csr<false><<<N_NODES / 8, 256, 0, stream>>>(
          (const __half2*)xc, row_start, adj, (__half2*)xn, (float2*)prop);
    }
    __half* tmp = xc; xc = xn; xn = tmp;
  }

  tail_kernel<<<N_NODES / 32, 256, 0, stream>>>(prop, b0, W0Th, W1Th, b1, out);
}

// Round 12
// 484.239 us; speedup vs baseline: 2.0918x; 1.0431x over previous
//
#include <hip/hip_runtime.h>
#include <hip/hip_fp16.h>
#include <math.h>

#define N_NODES 100000
#define N_EDGES 1600000
#define NF 64
#define ORDER 8
#define NBLK 391          // ceil(N_NODES/256)
#define MAX_ADJ (N_EDGES + 8 * N_NODES)   // padded upper bound
#define NPR (N_NODES / 8)                 // nodes per XCD dst-range, 12500

struct __align__(8) H4 { __half2 a, b; };   // 4 halves

using f16x8 = __attribute__((ext_vector_type(8))) _Float16;
using f32x4 = __attribute__((ext_vector_type(4))) float;

// ---------------- CSR build (once per launch) ----------------

__global__ __launch_bounds__(256) void zero_ints(int* __restrict__ c, int n) {
  int i = blockIdx.x * 256 + threadIdx.x;
  if (i < n) c[i] = 0;
}

__global__ __launch_bounds__(256) void hist_kernel(const int* __restrict__ dst,
                                                   int* __restrict__ counts) {
  int e = blockIdx.x * 256 + threadIdx.x;
  if (e < N_EDGES) atomicAdd(&counts[dst[e]], 1);
}

// padded count: round deg up to multiple of 8 (uniform PF spmm loop)
__device__ __forceinline__ int padc(int c) { return (c + 7) & ~7; }

__global__ __launch_bounds__(256) void reduce_counts(const int* __restrict__ counts,
                                                     int* __restrict__ blockSums) {
  int i = blockIdx.x * 256 + threadIdx.x;
  int v = (i < N_NODES) ? padc(counts[i]) : 0;
  #pragma unroll
  for (int m = 1; m < 64; m <<= 1) v += __shfl_xor(v, m, 64);
  __shared__ int s[4];
  if ((threadIdx.x & 63) == 0) s[threadIdx.x >> 6] = v;
  __syncthreads();
  if (threadIdx.x == 0) blockSums[blockIdx.x] = s[0] + s[1] + s[2] + s[3];
}

__global__ __launch_bounds__(512) void scan_partials(const int* __restrict__ blockSums,
                                                     int* __restrict__ blockOffs) {
  __shared__ int s[512];
  int t = threadIdx.x;
  int v = (t < NBLK) ? blockSums[t] : 0;
  s[t] = v;
  __syncthreads();
  for (int off = 1; off < 512; off <<= 1) {
    int u = (t >= off) ? s[t - off] : 0;
    __syncthreads();
    s[t] += u;
    __syncthreads();
  }
  if (t < NBLK) blockOffs[t] = s[t] - v;   // exclusive
}

__global__ __launch_bounds__(256) void scan_blocks(const int* __restrict__ counts,
    const int* __restrict__ blockOffs, int* __restrict__ row_start,
    int* __restrict__ cursor) {
  __shared__ int s[256];
  int t = threadIdx.x;
  int i = blockIdx.x * 256 + t;
  int v = (i < N_NODES) ? padc(counts[i]) : 0;
  s[t] = v;
  __syncthreads();
  for (int off = 1; off < 256; off <<= 1) {
    int u = (t >= off) ? s[t - off] : 0;
    __syncthreads();
    s[t] += u;
    __syncthreads();
  }
  int excl = s[t] - v + blockOffs[blockIdx.x];
  if (i < N_NODES) { row_start[i] = excl; cursor[i] = excl; }
  if (i == N_NODES - 1) row_start[N_NODES] = excl + v;
}

// XCD-partitioned fill: block (chunk = blockIdx>>3) handles only edges whose
// dst falls in range (blockIdx&7). blockIdx%8 -> XCD round-robin, so each
// cursor line / adj region is touched by exactly one XCD: atomics stay
// XCD-local, adj lines fill up in L2 before eviction.
// packed adj entry: src (17 bits) << 15 | weight as 15-bit fixed point.
__global__ __launch_bounds__(256) void fill_kernel(const int* __restrict__ src,
    const int* __restrict__ dst, const float* __restrict__ ew,
    int* __restrict__ cursor, unsigned int* __restrict__ adj) {
  const int rg = blockIdx.x & 7;
  const int e = (blockIdx.x >> 3) * 256 + threadIdx.x;
  if (e >= N_EDGES) return;
  int d = dst[e];
  if ((unsigned)(d - rg * NPR) >= (unsigned)NPR) return;
  int pos = atomicAdd(&cursor[d], 1);
  unsigned int w15 = (unsigned int)rintf(ew[e] * 32767.0f);
  adj[pos] = ((unsigned int)src[e] << 15) | w15;
}

// Pack weights fp16 transposed: W0Th[256 n][64 k] = W0[k][n]; W1Th[48 c][256 k] = W1[k][c]
__global__ __launch_bounds__(256) void pack_weights(const float* __restrict__ W0,
    const float* __restrict__ W1, _Float16* __restrict__ W0Th,
    _Float16* __restrict__ W1Th) {
  int t = threadIdx.x;   // one block of 256
  for (int k = 0; k < 64; ++k)
    W0Th[t * 64 + k] = (_Float16)W0[k * 256 + t];
  for (int c = 0; c < 48; ++c) {
    float v = (c < 47) ? W1[t * 47 + c] : 0.0f;
    W1Th[c * 256 + t] = (_Float16)v;
  }
}

// ---------------- propagation ----------------

// x_cur = fp16(X*0.5) ; prop = fp32(X*0.5)
__global__ __launch_bounds__(256) void init_kernel(const float4* __restrict__ X,
    H4* __restrict__ xc, float4* __restrict__ prop, int n4) {
  int i = blockIdx.x * 256 + threadIdx.x;
  if (i >= n4) return;
  float4 v = X[i];
  v.x *= 0.5f; v.y *= 0.5f; v.z *= 0.5f; v.w *= 0.5f;
  prop[i] = v;
  H4 h;
  h.a = __floats2half2_rn(v.x, v.y);
  h.b = __floats2half2_rn(v.z, v.w);
  xc[i] = h;
}

// gather-sum per dst node: 32 lanes/node, half2/lane, fp32 accumulate.
// Rows padded to 8 -> uniform batches; 2-deep batch pipeline (16 gathers in flight).
template<bool ACC>
__global__ __launch_bounds__(256) void spmm_csr(const __half2* __restrict__ x,
    const int* __restrict__ row_start, const unsigned int* __restrict__ adj,
    __half2* __restrict__ xn, float2* __restrict__ prop) {
  const int node = blockIdx.x * 8 + (threadIdx.x >> 5);   // 100000 % 8 == 0
  const int f2 = threadIdx.x & 31;
  const int beg = row_start[node];
  const int nb = (row_start[node + 1] - beg) >> 3;
  const size_t o = (size_t)node * 32 + f2;
  float2 xin;
  if (ACC) xin = __half22float2(x[o]);
  float2 a0 = make_float2(0.f, 0.f), a1 = a0;

  unsigned int e0[8] = {0}, e1[8] = {0};
  __half2 v0[8], v1[8];
  if (nb > 0) {
    #pragma unroll
    for (int j = 0; j < 8; ++j) e0[j] = adj[beg + j];
    #pragma unroll
    for (int j = 0; j < 8; ++j) v0[j] = x[(size_t)(e0[j] >> 15) * 32 + f2];
  }
  if (nb > 1) {
    #pragma unroll
    for (int j = 0; j < 8; ++j) e1[j] = adj[beg + 8 + j];
    #pragma unroll
    for (int j = 0; j < 8; ++j) v1[j] = x[(size_t)(e1[j] >> 15) * 32 + f2];
  }
  for (int b = 0; b < nb; ++b) {
    // consume batch in slot 0
    #pragma unroll
    for (int j = 0; j < 8; ++j) {
      float w = (float)(e0[j] & 0x7fffu) * (1.0f / 32767.0f);
      float2 f = __half22float2(v0[j]);
      if (j & 1) { a1.x = fmaf(f.x, w, a1.x); a1.y = fmaf(f.y, w, a1.y); }
      else       { a0.x = fmaf(f.x, w, a0.x); a0.y = fmaf(f.y, w, a0.y); }
    }
    // rotate pipeline
    #pragma unroll
    for (int j = 0; j < 8; ++j) { e0[j] = e1[j]; v0[j] = v1[j]; }
    if (b + 2 < nb) {
      const int q = beg + 8 * (b + 2);
      #pragma unroll
      for (int j = 0; j < 8; ++j) e1[j] = adj[q + j];
      #pragma unroll
      for (int j = 0; j < 8; ++j) v1[j] = x[(size_t)(e1[j] >> 15) * 32 + f2];
    }
  }
  a0.x += a1.x; a0.y += a1.y;
  xn[o] = __floats2half2_rn(a0.x, a0.y);
  if (ACC) {
    float2 pr = prop[o];
    pr.x += xin.x + a0.x;
    pr.y += xin.y + a0.y;
    prop[o] = pr;
  }
}

// ---------------- fused tail, MFMA fp16 (unchanged from R10) ----------------
__global__ __launch_bounds__(256) void tail_kernel(
    const float* __restrict__ prop, const float* __restrict__ b0,
    const _Float16* __restrict__ W0Th, const _Float16* __restrict__ W1Th,
    const float* __restrict__ b1, float* __restrict__ out) {
  __shared__ __align__(16) _Float16 sXp[32][72];
  __shared__ __align__(16) _Float16 sH[32][264];
  __shared__ float sPart[32][8];
  __shared__ float sHinv[32];

  const int t = threadIdx.x;
  const int lane = t & 63;
  const int w = t >> 6;
  const int l15 = lane & 15;
  const int l4 = lane >> 4;
  const int base = blockIdx.x * 32;   // 3125 * 32 == 100000 exactly

  #pragma unroll
  for (int it = 0; it < 8; ++it) {
    const int nb = it * 4 + w;
    float v = prop[(size_t)(base + nb) * NF + lane];
    float ss = v * v;
    #pragma unroll
    for (int m = 1; m < 64; m <<= 1) ss += __shfl_xor(ss, m, 64);
    float nrm = sqrtf(ss) * (1.0f / 9.0f);
    float scale = (1.0f / 9.0f) / (1e-12f + nrm);
    sXp[nb][lane] = (_Float16)(v * scale);
  }
  __syncthreads();

  f32x4 acc1[2][4];
  #pragma unroll
  for (int j = 0; j < 4; ++j) {
    float bv = b0[(w * 4 + j) * 16 + l15];
    #pragma unroll
    for (int mt = 0; mt < 2; ++mt)
      acc1[mt][j] = (f32x4){bv, bv, bv, bv};
  }
  #pragma unroll
  for (int ks = 0; ks < 2; ++ks) {
    const int koff = l4 * 8 + ks * 32;
    f16x8 a0 = *(const f16x8*)&sXp[l15][koff];
    f16x8 a1 = *(const f16x8*)&sXp[16 + l15][koff];
    #pragma unroll
    for (int j = 0; j < 4; ++j) {
      f16x8 b = *(const f16x8*)&W0Th[(size_t)((w * 4 + j) * 16 + l15) * 64 + koff];
      acc1[0][j] = __builtin_amdgcn_mfma_f32_16x16x32_f16(a0, b, acc1[0][j], 0, 0, 0);
      acc1[1][j] = __builtin_amdgcn_mfma_f32_16x16x32_f16(a1, b, acc1[1][j], 0, 0, 0);
    }
  }

  #pragma unroll
  for (int mt = 0; mt < 2; ++mt) {
    #pragma unroll
    for (int r = 0; r < 4; ++r) {
      float s = 0.0f;
      #pragma unroll
      for (int j = 0; j < 4; ++j) {
        float x = fmaxf(acc1[mt][j][r], 0.0f);
        acc1[mt][j][r] = x;
        s = fmaf(x, x, s);
      }
      #pragma unroll
      for (int m = 1; m < 16; m <<= 1) s += __shfl_xor(s, m, 64);
      if (l15 == 0) sPart[mt * 16 + l4 * 4 + r][w] = s;
    }
  }
  __syncthreads();

  if (t < 32) {
    float s = sPart[t][0] + sPart[t][1] + sPart[t][2] + sPart[t][3];
    sHinv[t] = 1.0f / (1e-12f + sqrtf(s));
  }
  __syncthreads();

  #pragma unroll
  for (int mt = 0; mt < 2; ++mt) {
    #pragma unroll
    for (int r = 0; r < 4; ++r) {
      const int row = mt * 16 + l4 * 4 + r;
      const float sc = sHinv[row];
      #pragma unroll
      for (int j = 0; j < 4; ++j)
        sH[row][(w * 4 + j) * 16 + l15] = (_Float16)(acc1[mt][j][r] * sc);
    }
  }
  __syncthreads();

  if (w < 3) {
    const int c = w * 16 + l15;
    float bv = (c < 47) ? b1[c] : 0.0f;
    f32x4 acc2[2];
    acc2[0] = (f32x4){bv, bv, bv, bv};
    acc2[1] = (f32x4){bv, bv, bv, bv};
    #pragma unroll
    for (int ks = 0; ks < 8; ++ks) {
      const int koff = l4 * 8 + ks * 32;
      f16x8 b = *(const f16x8*)&W1Th[(size_t)(w * 16 + l15) * 256 + koff];
      f16x8 a0 = *(const f16x8*)&sH[l15][koff];
      f16x8 a1 = *(const f16x8*)&sH[16 + l15][koff];
      acc2[0] = __builtin_amdgcn_mfma_f32_16x16x32_f16(a0, b, acc2[0], 0, 0, 0);
      acc2[1] = __builtin_amdgcn_mfma_f32_16x16x32_f16(a1, b, acc2[1], 0, 0, 0);
    }
    if (c < 47) {
      #pragma unroll
      for (int mt = 0; mt < 2; ++mt) {
        #pragma unroll
        for (int r = 0; r < 4; ++r) {
          const int node = base + mt * 16 + l4 * 4 + r;
          out[(size_t)node * 47 + c] = acc2[mt][r];
        }
      }
    }
  }
}

extern "C" void kernel_launch(void* const* d_in, const int* in_sizes, int n_in,
                              void* d_out, int out_size, void* d_ws, size_t ws_size,
                              hipStream_t stream) {
  (void)in_sizes; (void)n_in; (void)out_size; (void)ws_size;
  const float* X   = (const float*)d_in[0];
  const int*   src = (const int*)d_in[1];
  const int*   dst = (const int*)d_in[2];
  const float* ew  = (const float*)d_in[3];
  const float* W0  = (const float*)d_in[4];
  const float* b0  = (const float*)d_in[5];
  const float* W1  = (const float*)d_in[6];
  const float* b1  = (const float*)d_in[7];
  float* out = (float*)d_out;

  const size_t nf = (size_t)N_NODES * NF;    // 6.4M elements
  __half* bufA = (__half*)d_ws;              // 12.8 MB
  __half* bufB = bufA + nf;                  // 12.8 MB
  float*  prop = (float*)(bufB + nf);        // 25.6 MB
  int* counts     = (int*)(prop + nf);
  int* row_start  = counts + N_NODES;        // N_NODES+1
  int* cursor     = row_start + (N_NODES + 1);
  int* blockSums  = cursor + N_NODES;
  int* blockOffs  = blockSums + NBLK;
  _Float16* W0Th  = (_Float16*)(((uintptr_t)(blockOffs + NBLK) + 15) & ~(uintptr_t)15);
  _Float16* W1Th  = W0Th + 256 * 64;
  unsigned int* adj = (unsigned int*)(((uintptr_t)(W1Th + 48 * 256) + 15) & ~(uintptr_t)15);

  const int eblocks = (N_EDGES + 255) / 256;

  zero_ints<<<NBLK, 256, 0, stream>>>(counts, N_NODES);
  hipMemsetAsync(adj, 0, (size_t)MAX_ADJ * 4, stream);   // pad entries = (src 0, w 0)
  hist_kernel<<<eblocks, 256, 0, stream>>>(dst, counts);
  reduce_counts<<<NBLK, 256, 0, stream>>>(counts, blockSums);
  scan_partials<<<1, 512, 0, stream>>>(blockSums, blockOffs);
  scan_blocks<<<NBLK, 256, 0, stream>>>(counts, blockOffs, row_start, cursor);
  fill_kernel<<<8 * eblocks, 256, 0, stream>>>(src, dst, ew, cursor, adj);
  pack_weights<<<1, 256, 0, stream>>>(W0, W1, W0Th, W1Th);

  const int n4 = (int)(nf / 4);
  init_kernel<<<(n4 + 255) / 256, 256, 0, stream>>>(
      (const float4*)X, (H4*)bufA, (float4*)prop, n4);

  __half* xc = bufA;
  __half* xn = bufB;
  for (int r = 0; r < ORDER; ++r) {
    if (r & 1) {
      spmm_csr<true><<<N_NODES / 8, 256, 0, stream>>>(
          (const __half2*)xc, row_start, adj, (__half2*)xn, (float2*)prop);
    } else {
      spmm_csr<false><<<N_NODES / 8, 256, 0, stream>>>(
          (const __half2*)xc, row_start, adj, (__half2*)xn, (float2*)prop);
    }
    __half* tmp = xc; xc = xn; xn = tmp;
  }

  tail_kernel<<<N_NODES / 32, 256, 0, stream>>>(prop, b0, W0Th, W1Th, b1, out);
}